// Round 1
// baseline (806.563 us; speedup 1.0000x reference)
//
#include <hip/hip_runtime.h>

#define IN_C 128
#define HID_C 128
#define OUT_C 64
#define BN_EPS 1e-5f

// ---------------- CSR construction ----------------

__global__ void k_init(int* cnt, int* fillc, float* stats, int n) {
  int i = blockIdx.x * 256 + threadIdx.x;
  if (i < n) { cnt[i] = 0; fillc[i] = 0; }
  if (i < 256) stats[i] = 0.f;
}

__global__ void k_count(const int* __restrict__ col, int* __restrict__ cnt, int e) {
  int i = blockIdx.x * 256 + threadIdx.x;
  if (i < e) atomicAdd(&cnt[col[i]], 1);
}

// block-local exclusive scan of cnt -> rowptr (pre-offset); also deg^-1/2
__global__ void k_scan1(const int* __restrict__ cnt, int* __restrict__ rowptr,
                        int* __restrict__ bsum, float* __restrict__ dis, int n) {
  __shared__ int sd[256];
  int tid = threadIdx.x;
  int i = blockIdx.x * 256 + tid;
  int v = (i < n) ? cnt[i] : 0;
  if (i < n) dis[i] = rsqrtf((float)(v + 1));  // +1 self loop
  sd[tid] = v;
  __syncthreads();
  for (int off = 1; off < 256; off <<= 1) {
    int t = (tid >= off) ? sd[tid - off] : 0;
    __syncthreads();
    sd[tid] += t;
    __syncthreads();
  }
  if (i < n) rowptr[i] = sd[tid] - v;          // exclusive
  if (tid == 255) bsum[blockIdx.x] = sd[255];
}

__global__ void k_scan2(int* bsum, int nb, int* rowptr, int n) {
  if (threadIdx.x == 0 && blockIdx.x == 0) {
    int acc = 0;
    for (int b = 0; b < nb; b++) { int t = bsum[b]; bsum[b] = acc; acc += t; }
    rowptr[n] = acc;
  }
}

__global__ void k_scan3(int* rowptr, const int* __restrict__ bsum, int n) {
  int i = blockIdx.x * 256 + threadIdx.x;
  if (i < n) rowptr[i] += bsum[blockIdx.x];
}

__global__ void k_fill(const int* __restrict__ row, const int* __restrict__ col,
                       const int* __restrict__ rowptr, int* __restrict__ fillc,
                       int* __restrict__ srcidx, int e) {
  int i = blockIdx.x * 256 + threadIdx.x;
  if (i < e) {
    int c = col[i];
    int pos = atomicAdd(&fillc[c], 1);
    srcidx[rowptr[c] + pos] = row[i];
  }
}

// ---------------- GEMM1: h1 = x @ W1  [N,128]x[128,128] ----------------

__global__ __launch_bounds__(128) void k_gemm1(const float* __restrict__ x,
                                               const float* __restrict__ W,
                                               float* __restrict__ h1, int n) {
  __shared__ float xs[8][IN_C];
  int tid = threadIdx.x;
  int base = blockIdx.x * 8;
#pragma unroll
  for (int r = 0; r < 8; r++) {
    int rowi = base + r;
    xs[r][tid] = (rowi < n) ? x[(size_t)rowi * IN_C + tid] : 0.f;
  }
  __syncthreads();
  float acc[8] = {};
  for (int k = 0; k < IN_C; k += 4) {
    float w0 = W[(k + 0) * HID_C + tid];
    float w1 = W[(k + 1) * HID_C + tid];
    float w2 = W[(k + 2) * HID_C + tid];
    float w3 = W[(k + 3) * HID_C + tid];
#pragma unroll
    for (int r = 0; r < 8; r++) {
      float4 xv = *reinterpret_cast<const float4*>(&xs[r][k]);
      acc[r] += xv.x * w0 + xv.y * w1 + xv.z * w2 + xv.w * w3;
    }
  }
#pragma unroll
  for (int r = 0; r < 8; r++) {
    int rowi = base + r;
    if (rowi < n) h1[(size_t)rowi * HID_C + tid] = acc[r];
  }
}

// ---------------- SpMM1: agg = D^-1/2 A D^-1/2 h1 + b1 ----------------

__global__ __launch_bounds__(256) void k_spmm1(const float* __restrict__ h1,
                                               const float* __restrict__ dis,
                                               const int* __restrict__ rowptr,
                                               const int* __restrict__ srcidx,
                                               const float* __restrict__ b1,
                                               float* __restrict__ agg, int n) {
  int tid = threadIdx.x;
  int c = tid & (HID_C - 1);
  int i = blockIdx.x * 2 + (tid >> 7);
  if (i >= n) return;
  float di = dis[i];
  float acc = di * h1[(size_t)i * HID_C + c];  // self loop (di*di after final mul)
  int s = rowptr[i], t = rowptr[i + 1];
  for (int p = s; p < t; p++) {
    int j = srcidx[p];
    acc += dis[j] * h1[(size_t)j * HID_C + c];
  }
  agg[(size_t)i * HID_C + c] = di * acc + b1[c];
}

// ---------------- BN stats ----------------

__global__ __launch_bounds__(256) void k_bnstats(const float* __restrict__ agg,
                                                 float* __restrict__ stats, int n) {
  __shared__ float ls[256], lq[256];
  int tid = threadIdx.x;
  int c = tid & 127;
  int half = tid >> 7;
  float s = 0.f, q = 0.f;
  for (int rowi = blockIdx.x * 2 + half; rowi < n; rowi += gridDim.x * 2) {
    float v = agg[(size_t)rowi * HID_C + c];
    s += v;
    q += v * v;
  }
  ls[tid] = s; lq[tid] = q;
  __syncthreads();
  if (tid < 128) {
    s = ls[tid] + ls[tid + 128];
    q = lq[tid] + lq[tid + 128];
    atomicAdd(&stats[tid], s);
    atomicAdd(&stats[128 + tid], q);
  }
}

__global__ void k_bnfinal(const float* __restrict__ stats, const float* __restrict__ gamma,
                          const float* __restrict__ beta, float* __restrict__ bnp, int n) {
  int c = threadIdx.x;
  if (c < 128) {
    float inv_n = 1.f / (float)n;
    float mean = stats[c] * inv_n;
    float var = stats[128 + c] * inv_n - mean * mean;
    float istd = rsqrtf(var + BN_EPS);
    float sc = gamma[c] * istd;
    bnp[c] = sc;
    bnp[128 + c] = beta[c] - mean * sc;
  }
}

// ------- GEMM2 (BN+ReLU fused on load): h2 = relu(bn(agg)) @ W2, in-place rows -------

__global__ __launch_bounds__(128) void k_gemm2(float* __restrict__ agg,
                                               const float* __restrict__ W2,
                                               const float* __restrict__ bnp, int n) {
  __shared__ float ls[16][HID_C];
  int tid = threadIdx.x;
  int base = blockIdx.x * 16;
#pragma unroll
  for (int r = 0; r < 16; r++) {
    int rowi = base + r;
    if (rowi < n) {
      float v = agg[(size_t)rowi * HID_C + tid];
      v = v * bnp[tid] + bnp[HID_C + tid];
      ls[r][tid] = v > 0.f ? v : 0.f;
    } else {
      ls[r][tid] = 0.f;
    }
  }
  __syncthreads();
  int c = tid & 63;
  int rbase = (tid >> 6) * 8;
  float acc[8] = {};
  for (int k = 0; k < HID_C; k += 4) {
    float w0 = W2[(k + 0) * OUT_C + c];
    float w1 = W2[(k + 1) * OUT_C + c];
    float w2 = W2[(k + 2) * OUT_C + c];
    float w3 = W2[(k + 3) * OUT_C + c];
#pragma unroll
    for (int r = 0; r < 8; r++) {
      float4 xv = *reinterpret_cast<const float4*>(&ls[rbase + r][k]);
      acc[r] += xv.x * w0 + xv.y * w1 + xv.z * w2 + xv.w * w3;
    }
  }
#pragma unroll
  for (int r = 0; r < 8; r++) {
    int rowi = base + rbase + r;
    if (rowi < n) agg[(size_t)rowi * HID_C + c] = acc[r];  // h2 stored stride-128
  }
}

// ---------------- SpMM2 -> out ----------------

__global__ __launch_bounds__(256) void k_spmm2(const float* __restrict__ h2,
                                               const float* __restrict__ dis,
                                               const int* __restrict__ rowptr,
                                               const int* __restrict__ srcidx,
                                               const float* __restrict__ b2,
                                               float* __restrict__ out, int n) {
  int tid = threadIdx.x;
  int c = tid & 63;
  int i = blockIdx.x * 4 + (tid >> 6);
  if (i >= n) return;
  float di = dis[i];
  float acc = di * h2[(size_t)i * HID_C + c];
  int s = rowptr[i], t = rowptr[i + 1];
  for (int p = s; p < t; p++) {
    int j = srcidx[p];
    acc += dis[j] * h2[(size_t)j * HID_C + c];
  }
  out[(size_t)i * OUT_C + c] = di * acc + b2[c];
}

// ---------------- launch ----------------

extern "C" void kernel_launch(void* const* d_in, const int* in_sizes, int n_in,
                              void* d_out, int out_size, void* d_ws, size_t ws_size,
                              hipStream_t stream) {
  const float* x     = (const float*)d_in[0];
  const int*   edge  = (const int*)d_in[1];
  const float* W1    = (const float*)d_in[2];
  const float* b1    = (const float*)d_in[3];
  const float* gamma = (const float*)d_in[4];
  const float* beta  = (const float*)d_in[5];
  const float* W2    = (const float*)d_in[6];
  const float* b2    = (const float*)d_in[7];
  float* out = (float*)d_out;

  int n = in_sizes[0] / IN_C;
  int e = in_sizes[1] / 2;
  const int* row = edge;      // edge_index[0] = source j
  const int* col = edge + e;  // edge_index[1] = target i

  char* ws = (char*)d_ws;
  size_t off = 0;
  auto alloc = [&](size_t bytes) {
    void* p = ws + off;
    off = (off + bytes + 255) & ~(size_t)255;
    return p;
  };
  float* dis   = (float*)alloc((size_t)n * 4);
  int*   cnt   = (int*)alloc((size_t)n * 4);
  int*   rowp  = (int*)alloc((size_t)(n + 1) * 4);
  int*   fillc = (int*)alloc((size_t)n * 4);
  int*   bsum  = (int*)alloc(4096);
  int*   srci  = (int*)alloc((size_t)e * 4);
  float* h1    = (float*)alloc((size_t)n * HID_C * 4);
  float* agg   = (float*)alloc((size_t)n * HID_C * 4);
  float* stats = (float*)alloc(256 * 4);
  float* bnp   = (float*)alloc(256 * 4);
  (void)ws_size; (void)n_in; (void)out_size;

  int nb_n = (n + 255) / 256;
  int nb_e = (e + 255) / 256;

  k_init   <<<nb_n, 256, 0, stream>>>(cnt, fillc, stats, n);
  k_count  <<<nb_e, 256, 0, stream>>>(col, cnt, e);
  k_scan1  <<<nb_n, 256, 0, stream>>>(cnt, rowp, bsum, dis, n);
  k_scan2  <<<1, 1, 0, stream>>>(bsum, nb_n, rowp, n);
  k_scan3  <<<nb_n, 256, 0, stream>>>(rowp, bsum, n);
  k_fill   <<<nb_e, 256, 0, stream>>>(row, col, rowp, fillc, srci, e);
  k_gemm1  <<<(n + 7) / 8, 128, 0, stream>>>(x, W1, h1, n);
  k_spmm1  <<<(n + 1) / 2, 256, 0, stream>>>(h1, dis, rowp, srci, b1, agg, n);
  k_bnstats<<<512, 256, 0, stream>>>(agg, stats, n);
  k_bnfinal<<<1, 128, 0, stream>>>(stats, gamma, beta, bnp, n);
  k_gemm2  <<<(n + 15) / 16, 128, 0, stream>>>(agg, W2, bnp, n);
  k_spmm2  <<<(n + 3) / 4, 256, 0, stream>>>(agg, dis, rowp, srci, b2, out, n);
}

// Round 2
// 526.509 us; speedup vs baseline: 1.5319x; 1.5319x over previous
//
#include <hip/hip_runtime.h>

#define IN_C 128
#define HID_C 128
#define OUT_C 64
#define BN_EPS 1e-5f

// ---------------- CSR construction ----------------

__global__ void k_init(int* cnt, int* fillc, float* stats, int n) {
  int i = blockIdx.x * 256 + threadIdx.x;
  if (i < n) { cnt[i] = 0; fillc[i] = 0; }
  if (i < 256) stats[i] = 0.f;
}

__global__ void k_count(const int* __restrict__ col, int* __restrict__ cnt, int e) {
  int i = blockIdx.x * 256 + threadIdx.x;
  if (i < e) atomicAdd(&cnt[col[i]], 1);
}

// block-local exclusive scan of cnt -> rowptr (pre-offset); also deg^-1/2
__global__ void k_scan1(const int* __restrict__ cnt, int* __restrict__ rowptr,
                        int* __restrict__ bsum, float* __restrict__ dis, int n) {
  __shared__ int sd[256];
  int tid = threadIdx.x;
  int i = blockIdx.x * 256 + tid;
  int v = (i < n) ? cnt[i] : 0;
  if (i < n) dis[i] = rsqrtf((float)(v + 1));  // +1 self loop
  sd[tid] = v;
  __syncthreads();
  for (int off = 1; off < 256; off <<= 1) {
    int t = (tid >= off) ? sd[tid - off] : 0;
    __syncthreads();
    sd[tid] += t;
    __syncthreads();
  }
  if (i < n) rowptr[i] = sd[tid] - v;          // exclusive
  if (tid == 255) bsum[blockIdx.x] = sd[255];
}

// one-block parallel scan of per-block sums (nb <= 512)
__global__ __launch_bounds__(512) void k_scan2(int* bsum, int nb, int* rowptr, int n) {
  __shared__ int sd[512];
  int tid = threadIdx.x;
  int v = (tid < nb) ? bsum[tid] : 0;
  sd[tid] = v;
  __syncthreads();
  for (int off = 1; off < 512; off <<= 1) {
    int t = (tid >= off) ? sd[tid - off] : 0;
    __syncthreads();
    sd[tid] += t;
    __syncthreads();
  }
  if (tid < nb) bsum[tid] = sd[tid] - v;       // exclusive block offsets
  if (tid == nb - 1) rowptr[n] = sd[tid];      // total
}

__global__ void k_scan3(int* rowptr, const int* __restrict__ bsum, int n) {
  int i = blockIdx.x * 256 + threadIdx.x;
  if (i < n) rowptr[i] += bsum[blockIdx.x];
}

__global__ void k_fill(const int* __restrict__ row, const int* __restrict__ col,
                       const int* __restrict__ rowptr, int* __restrict__ fillc,
                       int* __restrict__ srcidx, int e) {
  int i = blockIdx.x * 256 + threadIdx.x;
  if (i < e) {
    int c = col[i];
    int pos = atomicAdd(&fillc[c], 1);
    srcidx[rowptr[c] + pos] = row[i];
  }
}

// ---------------- GEMM1: h1 = x @ W1  [N,128]x[128,128] ----------------

__global__ __launch_bounds__(128) void k_gemm1(const float* __restrict__ x,
                                               const float* __restrict__ W,
                                               float* __restrict__ h1, int n) {
  __shared__ float xs[8][IN_C];
  int tid = threadIdx.x;
  int base = blockIdx.x * 8;
#pragma unroll
  for (int r = 0; r < 8; r++) {
    int rowi = base + r;
    xs[r][tid] = (rowi < n) ? x[(size_t)rowi * IN_C + tid] : 0.f;
  }
  __syncthreads();
  float acc[8] = {};
  for (int k = 0; k < IN_C; k += 4) {
    float w0 = W[(k + 0) * HID_C + tid];
    float w1 = W[(k + 1) * HID_C + tid];
    float w2 = W[(k + 2) * HID_C + tid];
    float w3 = W[(k + 3) * HID_C + tid];
#pragma unroll
    for (int r = 0; r < 8; r++) {
      float4 xv = *reinterpret_cast<const float4*>(&xs[r][k]);
      acc[r] += xv.x * w0 + xv.y * w1 + xv.z * w2 + xv.w * w3;
    }
  }
#pragma unroll
  for (int r = 0; r < 8; r++) {
    int rowi = base + r;
    if (rowi < n) h1[(size_t)rowi * HID_C + tid] = acc[r];
  }
}

// ------- SpMM (templated): out_i = di * (sum_j dis_j * h_j + di*h_i) + bias -------
// C channels per row, float4 per lane -> LPR = C/4 lanes per row,
// ROWS = 256/LPR rows per block. 8-edge ILP batches.

template <int C>
__global__ __launch_bounds__(256) void k_spmm(const float* __restrict__ h, int hstride,
                                              const float* __restrict__ dis,
                                              const int* __restrict__ rowptr,
                                              const int* __restrict__ srcidx,
                                              const float* __restrict__ bias,
                                              float* __restrict__ outp, int ostride,
                                              int n) {
  constexpr int LPR = C / 4;
  constexpr int ROWS = 256 / LPR;
  int tid = threadIdx.x;
  int lane = tid & (LPR - 1);
  int r = tid / LPR;
  int i = blockIdx.x * ROWS + r;
  if (i >= n) return;
  int c4 = lane * 4;

  float di = dis[i];
  const float4 hv = *reinterpret_cast<const float4*>(&h[(size_t)i * hstride + c4]);
  float ax = di * hv.x, ay = di * hv.y, az = di * hv.z, aw = di * hv.w;

  int s = rowptr[i], t = rowptr[i + 1];
  int p = s;
  for (; p + 8 <= t; p += 8) {
    int j[8];
    float dj[8];
    float4 v[8];
#pragma unroll
    for (int k = 0; k < 8; k++) j[k] = srcidx[p + k];
#pragma unroll
    for (int k = 0; k < 8; k++) dj[k] = dis[j[k]];
#pragma unroll
    for (int k = 0; k < 8; k++)
      v[k] = *reinterpret_cast<const float4*>(&h[(size_t)j[k] * hstride + c4]);
#pragma unroll
    for (int k = 0; k < 8; k++) {
      ax += dj[k] * v[k].x;
      ay += dj[k] * v[k].y;
      az += dj[k] * v[k].z;
      aw += dj[k] * v[k].w;
    }
  }
  for (; p < t; p++) {
    int j = srcidx[p];
    float dj = dis[j];
    float4 v = *reinterpret_cast<const float4*>(&h[(size_t)j * hstride + c4]);
    ax += dj * v.x; ay += dj * v.y; az += dj * v.z; aw += dj * v.w;
  }

  float4 b4 = *reinterpret_cast<const float4*>(&bias[c4]);
  float4 res;
  res.x = di * ax + b4.x;
  res.y = di * ay + b4.y;
  res.z = di * az + b4.z;
  res.w = di * aw + b4.w;
  *reinterpret_cast<float4*>(&outp[(size_t)i * ostride + c4]) = res;
}

// ---------------- BN stats ----------------

__global__ __launch_bounds__(256) void k_bnstats(const float* __restrict__ agg,
                                                 float* __restrict__ stats, int n) {
  __shared__ float ls[256], lq[256];
  int tid = threadIdx.x;
  int c = tid & 127;
  int half = tid >> 7;
  float s = 0.f, q = 0.f;
  for (int rowi = blockIdx.x * 2 + half; rowi < n; rowi += gridDim.x * 2) {
    float v = agg[(size_t)rowi * HID_C + c];
    s += v;
    q += v * v;
  }
  ls[tid] = s; lq[tid] = q;
  __syncthreads();
  if (tid < 128) {
    s = ls[tid] + ls[tid + 128];
    q = lq[tid] + lq[tid + 128];
    atomicAdd(&stats[tid], s);
    atomicAdd(&stats[128 + tid], q);
  }
}

__global__ void k_bnfinal(const float* __restrict__ stats, const float* __restrict__ gamma,
                          const float* __restrict__ beta, float* __restrict__ bnp, int n) {
  int c = threadIdx.x;
  if (c < 128) {
    float inv_n = 1.f / (float)n;
    float mean = stats[c] * inv_n;
    float var = stats[128 + c] * inv_n - mean * mean;
    float istd = rsqrtf(var + BN_EPS);
    float sc = gamma[c] * istd;
    bnp[c] = sc;
    bnp[128 + c] = beta[c] - mean * sc;
  }
}

// ------- GEMM2 (BN+ReLU fused on load): h2 = relu(bn(agg)) @ W2, in-place rows -------

__global__ __launch_bounds__(128) void k_gemm2(float* __restrict__ agg,
                                               const float* __restrict__ W2,
                                               const float* __restrict__ bnp, int n) {
  __shared__ float ls[16][HID_C];
  int tid = threadIdx.x;
  int base = blockIdx.x * 16;
#pragma unroll
  for (int r = 0; r < 16; r++) {
    int rowi = base + r;
    if (rowi < n) {
      float v = agg[(size_t)rowi * HID_C + tid];
      v = v * bnp[tid] + bnp[HID_C + tid];
      ls[r][tid] = v > 0.f ? v : 0.f;
    } else {
      ls[r][tid] = 0.f;
    }
  }
  __syncthreads();
  int c = tid & 63;
  int rbase = (tid >> 6) * 8;
  float acc[8] = {};
  for (int k = 0; k < HID_C; k += 4) {
    float w0 = W2[(k + 0) * OUT_C + c];
    float w1 = W2[(k + 1) * OUT_C + c];
    float w2 = W2[(k + 2) * OUT_C + c];
    float w3 = W2[(k + 3) * OUT_C + c];
#pragma unroll
    for (int r = 0; r < 8; r++) {
      float4 xv = *reinterpret_cast<const float4*>(&ls[rbase + r][k]);
      acc[r] += xv.x * w0 + xv.y * w1 + xv.z * w2 + xv.w * w3;
    }
  }
#pragma unroll
  for (int r = 0; r < 8; r++) {
    int rowi = base + rbase + r;
    if (rowi < n) agg[(size_t)rowi * HID_C + c] = acc[r];  // h2 stored stride-128
  }
}

// ---------------- launch ----------------

extern "C" void kernel_launch(void* const* d_in, const int* in_sizes, int n_in,
                              void* d_out, int out_size, void* d_ws, size_t ws_size,
                              hipStream_t stream) {
  const float* x     = (const float*)d_in[0];
  const int*   edge  = (const int*)d_in[1];
  const float* W1    = (const float*)d_in[2];
  const float* b1    = (const float*)d_in[3];
  const float* gamma = (const float*)d_in[4];
  const float* beta  = (const float*)d_in[5];
  const float* W2    = (const float*)d_in[6];
  const float* b2    = (const float*)d_in[7];
  float* out = (float*)d_out;

  int n = in_sizes[0] / IN_C;
  int e = in_sizes[1] / 2;
  const int* row = edge;      // edge_index[0] = source j
  const int* col = edge + e;  // edge_index[1] = target i

  char* ws = (char*)d_ws;
  size_t off = 0;
  auto alloc = [&](size_t bytes) {
    void* p = ws + off;
    off = (off + bytes + 255) & ~(size_t)255;
    return p;
  };
  float* dis   = (float*)alloc((size_t)n * 4);
  int*   cnt   = (int*)alloc((size_t)n * 4);
  int*   rowp  = (int*)alloc((size_t)(n + 1) * 4);
  int*   fillc = (int*)alloc((size_t)n * 4);
  int*   bsum  = (int*)alloc(4096);
  int*   srci  = (int*)alloc((size_t)e * 4);
  float* h1    = (float*)alloc((size_t)n * HID_C * 4);
  float* agg   = (float*)alloc((size_t)n * HID_C * 4);
  float* stats = (float*)alloc(256 * 4);
  float* bnp   = (float*)alloc(256 * 4);
  (void)ws_size; (void)n_in; (void)out_size;

  int nb_n = (n + 255) / 256;
  int nb_e = (e + 255) / 256;

  k_init   <<<nb_n, 256, 0, stream>>>(cnt, fillc, stats, n);
  k_count  <<<nb_e, 256, 0, stream>>>(col, cnt, e);
  k_scan1  <<<nb_n, 256, 0, stream>>>(cnt, rowp, bsum, dis, n);
  k_scan2  <<<1, 512, 0, stream>>>(bsum, nb_n, rowp, n);
  k_scan3  <<<nb_n, 256, 0, stream>>>(rowp, bsum, n);
  k_fill   <<<nb_e, 256, 0, stream>>>(row, col, rowp, fillc, srci, e);
  k_gemm1  <<<(n + 7) / 8, 128, 0, stream>>>(x, W1, h1, n);
  // spmm1: 128 channels, 32 lanes/row, 8 rows/block
  k_spmm<HID_C><<<(n + 7) / 8, 256, 0, stream>>>(h1, HID_C, dis, rowp, srci, b1, agg, HID_C, n);
  k_bnstats<<<512, 256, 0, stream>>>(agg, stats, n);
  k_bnfinal<<<1, 128, 0, stream>>>(stats, gamma, beta, bnp, n);
  k_gemm2  <<<(n + 15) / 16, 128, 0, stream>>>(agg, W2, bnp, n);
  // spmm2: 64 channels (h2 stored stride-128 in agg), 16 lanes/row, 16 rows/block
  k_spmm<OUT_C><<<(n + 15) / 16, 256, 0, stream>>>(agg, HID_C, dis, rowp, srci, b2, out, OUT_C, n);
}

// Round 3
// 402.848 us; speedup vs baseline: 2.0022x; 1.3070x over previous
//
#include <hip/hip_runtime.h>

#define IN_C 128
#define HID_C 128
#define OUT_C 64
#define BN_EPS 1e-5f

typedef unsigned short ushort_t;
typedef __attribute__((ext_vector_type(8))) short bf16x8;
typedef __attribute__((ext_vector_type(4))) float f32x4;
typedef __attribute__((ext_vector_type(8))) unsigned short u16x8;

__device__ __forceinline__ float bf2f(ushort_t u) {
  union { unsigned i; float f; } c; c.i = (unsigned)u << 16; return c.f;
}
__device__ __forceinline__ ushort_t f2bf(float f) {
  union { float f; unsigned u; } c; c.f = f;
  unsigned r = c.u + 0x7FFF + ((c.u >> 16) & 1);
  return (ushort_t)(r >> 16);
}

// ---------------- CSR construction ----------------

__global__ void k_init(int* cnt, int* fillc, float* stats, int n) {
  int i = blockIdx.x * 256 + threadIdx.x;
  if (i < n) { cnt[i] = 0; fillc[i] = 0; }
  if (i < 256) stats[i] = 0.f;
}

__global__ void k_count(const int* __restrict__ col, int* __restrict__ cnt, int e) {
  int i = blockIdx.x * 256 + threadIdx.x;
  if (i < e) atomicAdd(&cnt[col[i]], 1);
}

__global__ void k_scan1(const int* __restrict__ cnt, int* __restrict__ rowptr,
                        int* __restrict__ bsum, float* __restrict__ dis, int n) {
  __shared__ int sd[256];
  int tid = threadIdx.x;
  int i = blockIdx.x * 256 + tid;
  int v = (i < n) ? cnt[i] : 0;
  if (i < n) dis[i] = rsqrtf((float)(v + 1));  // +1 self loop
  sd[tid] = v;
  __syncthreads();
  for (int off = 1; off < 256; off <<= 1) {
    int t = (tid >= off) ? sd[tid - off] : 0;
    __syncthreads();
    sd[tid] += t;
    __syncthreads();
  }
  if (i < n) rowptr[i] = sd[tid] - v;          // exclusive
  if (tid == 255) bsum[blockIdx.x] = sd[255];
}

__global__ __launch_bounds__(512) void k_scan2(int* bsum, int nb, int* rowptr, int n) {
  __shared__ int sd[512];
  int tid = threadIdx.x;
  int v = (tid < nb) ? bsum[tid] : 0;
  sd[tid] = v;
  __syncthreads();
  for (int off = 1; off < 512; off <<= 1) {
    int t = (tid >= off) ? sd[tid - off] : 0;
    __syncthreads();
    sd[tid] += t;
    __syncthreads();
  }
  if (tid < nb) bsum[tid] = sd[tid] - v;
  if (tid == nb - 1) rowptr[n] = sd[tid];
}

__global__ void k_scan3(int* rowptr, const int* __restrict__ bsum, int n) {
  int i = blockIdx.x * 256 + threadIdx.x;
  if (i < n) rowptr[i] += bsum[blockIdx.x];
}

__global__ void k_fill(const int* __restrict__ row, const int* __restrict__ col,
                       const int* __restrict__ rowptr, int* __restrict__ fillc,
                       int* __restrict__ srcidx, int e) {
  int i = blockIdx.x * 256 + threadIdx.x;
  if (i < e) {
    int c = col[i];
    int pos = atomicAdd(&fillc[c], 1);
    srcidx[rowptr[c] + pos] = row[i];
  }
}

// ---------------- weight pack: WB[n][k] = W[k][n] in bf16 ----------------

__global__ void k_wpack(const float* __restrict__ W1, const float* __restrict__ W2,
                        ushort_t* __restrict__ WB1, ushort_t* __restrict__ WB2) {
  int idx = blockIdx.x * 256 + threadIdx.x;
  if (idx < 128 * 128) {
    int nn = idx >> 7, k = idx & 127;
    WB1[idx] = f2bf(W1[k * HID_C + nn]);
  }
  int idx2 = idx - 128 * 128;
  if (idx2 >= 0 && idx2 < 64 * 128) {
    int nn = idx2 >> 7, k = idx2 & 127;
    WB2[idx2] = f2bf(W2[k * OUT_C + nn]);
  }
}

// ------- GEMM1 (MFMA bf16): h1 = bf16(x @ W1), [N,128]x[128,128] -------
// wave computes 16 rows x 128 cols; block = 4 waves = 64 rows.

__global__ __launch_bounds__(256) void k_gemm1_mfma(const float* __restrict__ x,
                                                    const ushort_t* __restrict__ WB,
                                                    ushort_t* __restrict__ h1, int n) {
  int wave = threadIdx.x >> 6;
  int lane = threadIdx.x & 63;
  int m = lane & 15;
  int kg = lane >> 4;
  int rowbase = blockIdx.x * 64 + wave * 16;
  int rrow = rowbase + m; if (rrow >= n) rrow = n - 1;
  const float* xrow = x + (size_t)rrow * IN_C + kg * 8;
  f32x4 acc[8] = {};
#pragma unroll
  for (int ks = 0; ks < 4; ks++) {
    float4 a0 = *reinterpret_cast<const float4*>(xrow + ks * 32);
    float4 a1 = *reinterpret_cast<const float4*>(xrow + ks * 32 + 4);
    bf16x8 a;
    a[0] = (short)f2bf(a0.x); a[1] = (short)f2bf(a0.y);
    a[2] = (short)f2bf(a0.z); a[3] = (short)f2bf(a0.w);
    a[4] = (short)f2bf(a1.x); a[5] = (short)f2bf(a1.y);
    a[6] = (short)f2bf(a1.z); a[7] = (short)f2bf(a1.w);
#pragma unroll
    for (int nt = 0; nt < 8; nt++) {
      bf16x8 b = *reinterpret_cast<const bf16x8*>(WB + (nt * 16 + m) * 128 + ks * 32 + kg * 8);
      acc[nt] = __builtin_amdgcn_mfma_f32_16x16x32_bf16(a, b, acc[nt], 0, 0, 0);
    }
  }
#pragma unroll
  for (int nt = 0; nt < 8; nt++)
#pragma unroll
    for (int r = 0; r < 4; r++) {
      int rowi = rowbase + kg * 4 + r;
      if (rowi < n) h1[(size_t)rowi * HID_C + nt * 16 + m] = f2bf(acc[nt][r]);
    }
}

// ------- GEMM2 (MFMA bf16, BN+ReLU fused on A-load): h2 = bf16(relu(bn(agg)) @ W2) -------

__global__ __launch_bounds__(256) void k_gemm2_mfma(const float* __restrict__ agg,
                                                    const ushort_t* __restrict__ WB,
                                                    const float* __restrict__ bnp,
                                                    ushort_t* __restrict__ h2, int n) {
  int wave = threadIdx.x >> 6;
  int lane = threadIdx.x & 63;
  int m = lane & 15;
  int kg = lane >> 4;
  int rowbase = blockIdx.x * 64 + wave * 16;
  int rrow = rowbase + m; if (rrow >= n) rrow = n - 1;
  const float* arow = agg + (size_t)rrow * HID_C + kg * 8;
  f32x4 acc[4] = {};
#pragma unroll
  for (int ks = 0; ks < 4; ks++) {
    int kbase = ks * 32 + kg * 8;
    float4 a0 = *reinterpret_cast<const float4*>(arow + ks * 32);
    float4 a1 = *reinterpret_cast<const float4*>(arow + ks * 32 + 4);
    float4 s0 = *reinterpret_cast<const float4*>(bnp + kbase);
    float4 s1 = *reinterpret_cast<const float4*>(bnp + kbase + 4);
    float4 t0 = *reinterpret_cast<const float4*>(bnp + 128 + kbase);
    float4 t1 = *reinterpret_cast<const float4*>(bnp + 128 + kbase + 4);
    float v[8];
    v[0] = a0.x * s0.x + t0.x; v[1] = a0.y * s0.y + t0.y;
    v[2] = a0.z * s0.z + t0.z; v[3] = a0.w * s0.w + t0.w;
    v[4] = a1.x * s1.x + t1.x; v[5] = a1.y * s1.y + t1.y;
    v[6] = a1.z * s1.z + t1.z; v[7] = a1.w * s1.w + t1.w;
    bf16x8 a;
#pragma unroll
    for (int q = 0; q < 8; q++) a[q] = (short)f2bf(v[q] > 0.f ? v[q] : 0.f);
#pragma unroll
    for (int nt = 0; nt < 4; nt++) {
      bf16x8 b = *reinterpret_cast<const bf16x8*>(WB + (nt * 16 + m) * 128 + ks * 32 + kg * 8);
      acc[nt] = __builtin_amdgcn_mfma_f32_16x16x32_bf16(a, b, acc[nt], 0, 0, 0);
    }
  }
#pragma unroll
  for (int nt = 0; nt < 4; nt++)
#pragma unroll
    for (int r = 0; r < 4; r++) {
      int rowi = rowbase + kg * 4 + r;
      if (rowi < n) h2[(size_t)rowi * OUT_C + nt * 16 + m] = f2bf(acc[nt][r]);
    }
}

// ------- SpMM (bf16 gather): out_i = di*(di*h_i + sum_j dj*h_j) + bias -------
// 8 channels per lane (16B bf16 load), LPR = C/8 lanes/row, 8-edge ILP batches.

template <int C>
__global__ __launch_bounds__(256) void k_spmm_bf(const ushort_t* __restrict__ h,
                                                 const float* __restrict__ dis,
                                                 const int* __restrict__ rowptr,
                                                 const int* __restrict__ srcidx,
                                                 const float* __restrict__ bias,
                                                 float* __restrict__ outp, int n) {
  constexpr int LPR = C / 8;
  constexpr int ROWS = 256 / LPR;
  int tid = threadIdx.x;
  int lane = tid & (LPR - 1);
  int r = tid / LPR;
  int i = blockIdx.x * ROWS + r;
  if (i >= n) return;
  int c8 = lane * 8;
  const ushort_t* hb = h + c8;

  float di = dis[i];
  float acc[8];
  u16x8 hv = *reinterpret_cast<const u16x8*>(hb + (size_t)i * C);
#pragma unroll
  for (int q = 0; q < 8; q++) acc[q] = di * bf2f(hv[q]);

  int s = rowptr[i], t = rowptr[i + 1];
  int p = s;
  for (; p + 8 <= t; p += 8) {
    int j[8]; float dj[8]; u16x8 v[8];
#pragma unroll
    for (int k = 0; k < 8; k++) j[k] = srcidx[p + k];
#pragma unroll
    for (int k = 0; k < 8; k++) dj[k] = dis[j[k]];
#pragma unroll
    for (int k = 0; k < 8; k++)
      v[k] = *reinterpret_cast<const u16x8*>(hb + (size_t)j[k] * C);
#pragma unroll
    for (int k = 0; k < 8; k++)
#pragma unroll
      for (int q = 0; q < 8; q++) acc[q] += dj[k] * bf2f(v[k][q]);
  }
  for (; p < t; p++) {
    int j = srcidx[p];
    float dj = dis[j];
    u16x8 v = *reinterpret_cast<const u16x8*>(hb + (size_t)j * C);
#pragma unroll
    for (int q = 0; q < 8; q++) acc[q] += dj * bf2f(v[q]);
  }

  float4 b0 = *reinterpret_cast<const float4*>(bias + c8);
  float4 b1v = *reinterpret_cast<const float4*>(bias + c8 + 4);
  float4 o0, o1;
  o0.x = di * acc[0] + b0.x;  o0.y = di * acc[1] + b0.y;
  o0.z = di * acc[2] + b0.z;  o0.w = di * acc[3] + b0.w;
  o1.x = di * acc[4] + b1v.x; o1.y = di * acc[5] + b1v.y;
  o1.z = di * acc[6] + b1v.z; o1.w = di * acc[7] + b1v.w;
  float* op = outp + (size_t)i * C + c8;
  *reinterpret_cast<float4*>(op) = o0;
  *reinterpret_cast<float4*>(op + 4) = o1;
}

// ---------------- BN stats ----------------

__global__ __launch_bounds__(256) void k_bnstats(const float* __restrict__ agg,
                                                 float* __restrict__ stats, int n) {
  __shared__ float ls[256], lq[256];
  int tid = threadIdx.x;
  int c = tid & 127;
  int half = tid >> 7;
  float s = 0.f, q = 0.f;
  for (int rowi = blockIdx.x * 2 + half; rowi < n; rowi += gridDim.x * 2) {
    float v = agg[(size_t)rowi * HID_C + c];
    s += v;
    q += v * v;
  }
  ls[tid] = s; lq[tid] = q;
  __syncthreads();
  if (tid < 128) {
    s = ls[tid] + ls[tid + 128];
    q = lq[tid] + lq[tid + 128];
    atomicAdd(&stats[tid], s);
    atomicAdd(&stats[128 + tid], q);
  }
}

__global__ void k_bnfinal(const float* __restrict__ stats, const float* __restrict__ gamma,
                          const float* __restrict__ beta, float* __restrict__ bnp, int n) {
  int c = threadIdx.x;
  if (c < 128) {
    float inv_n = 1.f / (float)n;
    float mean = stats[c] * inv_n;
    float var = stats[128 + c] * inv_n - mean * mean;
    float istd = rsqrtf(var + BN_EPS);
    float sc = gamma[c] * istd;
    bnp[c] = sc;
    bnp[128 + c] = beta[c] - mean * sc;
  }
}

// ---------------- launch ----------------

extern "C" void kernel_launch(void* const* d_in, const int* in_sizes, int n_in,
                              void* d_out, int out_size, void* d_ws, size_t ws_size,
                              hipStream_t stream) {
  const float* x     = (const float*)d_in[0];
  const int*   edge  = (const int*)d_in[1];
  const float* W1    = (const float*)d_in[2];
  const float* b1    = (const float*)d_in[3];
  const float* gamma = (const float*)d_in[4];
  const float* beta  = (const float*)d_in[5];
  const float* W2    = (const float*)d_in[6];
  const float* b2    = (const float*)d_in[7];
  float* out = (float*)d_out;

  int n = in_sizes[0] / IN_C;
  int e = in_sizes[1] / 2;
  int n64 = ((n + 63) / 64) * 64;
  const int* row = edge;      // edge_index[0] = source j
  const int* col = edge + e;  // edge_index[1] = target i

  char* ws = (char*)d_ws;
  size_t off = 0;
  auto alloc = [&](size_t bytes) {
    void* p = ws + off;
    off = (off + bytes + 255) & ~(size_t)255;
    return p;
  };
  float*    dis   = (float*)alloc((size_t)n * 4);
  int*      cnt   = (int*)alloc((size_t)n * 4);
  int*      rowp  = (int*)alloc((size_t)(n + 1) * 4);
  int*      fillc = (int*)alloc((size_t)n * 4);
  int*      bsum  = (int*)alloc(4096);
  int*      srci  = (int*)alloc((size_t)e * 4);
  ushort_t* WB1   = (ushort_t*)alloc(128 * 128 * 2);
  ushort_t* WB2   = (ushort_t*)alloc(64 * 128 * 2);
  ushort_t* h1b   = (ushort_t*)alloc((size_t)n64 * HID_C * 2);
  float*    agg   = (float*)alloc((size_t)n * HID_C * 4);
  ushort_t* h2b   = (ushort_t*)alloc((size_t)n64 * OUT_C * 2);
  float*    stats = (float*)alloc(256 * 4);
  float*    bnp   = (float*)alloc(256 * 4);
  (void)ws_size; (void)n_in; (void)out_size;

  int nb_n = (n + 255) / 256;
  int nb_e = (e + 255) / 256;
  int nb64 = n64 / 64;

  k_init      <<<nb_n, 256, 0, stream>>>(cnt, fillc, stats, n);
  k_count     <<<nb_e, 256, 0, stream>>>(col, cnt, e);
  k_scan1     <<<nb_n, 256, 0, stream>>>(cnt, rowp, bsum, dis, n);
  k_scan2     <<<1, 512, 0, stream>>>(bsum, nb_n, rowp, n);
  k_scan3     <<<nb_n, 256, 0, stream>>>(rowp, bsum, n);
  k_fill      <<<nb_e, 256, 0, stream>>>(row, col, rowp, fillc, srci, e);
  k_wpack     <<<96, 256, 0, stream>>>(W1, W2, WB1, WB2);
  k_gemm1_mfma<<<nb64, 256, 0, stream>>>(x, WB1, h1b, n);
  k_spmm_bf<HID_C><<<(n + 15) / 16, 256, 0, stream>>>(h1b, dis, rowp, srci, b1, agg, n);
  k_bnstats   <<<512, 256, 0, stream>>>(agg, stats, n);
  k_bnfinal   <<<1, 128, 0, stream>>>(stats, gamma, beta, bnp, n);
  k_gemm2_mfma<<<nb64, 256, 0, stream>>>(agg, WB2, bnp, h2b, n);
  k_spmm_bf<OUT_C><<<(n + 31) / 32, 256, 0, stream>>>(h2b, dis, rowp, srci, b2, out, n);
}

// Round 4
// 351.007 us; speedup vs baseline: 2.2979x; 1.1477x over previous
//
#include <hip/hip_runtime.h>

#define IN_C 128
#define HID_C 128
#define OUT_C 64
#define BN_EPS 1e-5f
#define BUCK_SHIFT 6            // 64 nodes per bucket
#define MAXBUCK 2048            // supports n up to 131071

typedef unsigned short ushort_t;
typedef __attribute__((ext_vector_type(8))) short bf16x8;
typedef __attribute__((ext_vector_type(4))) float f32x4;
typedef __attribute__((ext_vector_type(8))) unsigned short u16x8;

__device__ __forceinline__ float bf2f(ushort_t u) {
  union { unsigned i; float f; } c; c.i = (unsigned)u << 16; return c.f;
}
__device__ __forceinline__ ushort_t f2bf(float f) {
  union { float f; unsigned u; } c; c.f = f;
  unsigned r = c.u + 0x7FFF + ((c.u >> 16) & 1);
  return (ushort_t)(r >> 16);
}

// ---------------- misc init (stats only) ----------------

__global__ void k_init(float* stats) {
  stats[threadIdx.x] = 0.f;
}

// ---------------- CSR build via bucket counting sort (no global atomics) ----

// per-block LDS histogram over node-range buckets
__global__ __launch_bounds__(256) void k_hist(const int* __restrict__ col,
                                              int* __restrict__ ghist,
                                              int e, int nbuck, int chunk) {
  __shared__ int h[MAXBUCK];
  for (int p = threadIdx.x; p < nbuck; p += 256) h[p] = 0;
  __syncthreads();
  int s = blockIdx.x * chunk;
  int t = min(s + chunk, e);
  for (int i = s + threadIdx.x; i < t; i += 256)
    atomicAdd(&h[col[i] >> BUCK_SHIFT], 1);
  __syncthreads();
  int* gh = ghist + (size_t)blockIdx.x * nbuck;
  for (int p = threadIdx.x; p < nbuck; p += 256) gh[p] = h[p];
}

// per-bucket exclusive scan across blocks; ghist becomes per-(block,bucket) offset
__global__ __launch_bounds__(256) void k_s1(int* __restrict__ ghist,
                                            int* __restrict__ btotal,
                                            int nb, int nbuck) {
  int p = blockIdx.x * 256 + threadIdx.x;
  if (p >= nbuck) return;
  int run = 0;
  for (int b = 0; b < nb; b++) {
    int idx = b * nbuck + p;
    int v = ghist[idx];
    ghist[idx] = run;
    run += v;
  }
  btotal[p] = run;
}

// scan bucket totals -> bucketstart (exclusive); also rowptr[n] = e
__global__ __launch_bounds__(512) void k_s2(const int* __restrict__ btotal,
                                            int* __restrict__ bstart,
                                            int nbuck, int e,
                                            int* __restrict__ rowptr, int n) {
  __shared__ int sd[512];
  int tid = threadIdx.x;
  int base = tid * 4;
  int v[4]; int s = 0;
#pragma unroll
  for (int q = 0; q < 4; q++) {
    int i = base + q;
    v[q] = (i < nbuck) ? btotal[i] : 0;
    s += v[q];
  }
  sd[tid] = s;
  __syncthreads();
  for (int off = 1; off < 512; off <<= 1) {
    int t = (tid >= off) ? sd[tid - off] : 0;
    __syncthreads();
    sd[tid] += t;
    __syncthreads();
  }
  int run = sd[tid] - s;  // exclusive
#pragma unroll
  for (int q = 0; q < 4; q++) {
    int i = base + q;
    if (i < nbuck) bstart[i] = run;
    run += v[q];
  }
  if (tid == 0) { bstart[nbuck] = e; rowptr[n] = e; }
}

// scatter (col,row) pairs into bucket streams using LDS cursors
__global__ __launch_bounds__(256) void k_scatter(const int* __restrict__ row,
                                                 const int* __restrict__ col,
                                                 const int* __restrict__ ghist,
                                                 const int* __restrict__ bstart,
                                                 int* __restrict__ bcol,
                                                 int* __restrict__ brow,
                                                 int e, int nbuck, int chunk) {
  __shared__ int cur[MAXBUCK];
  const int* gh = ghist + (size_t)blockIdx.x * nbuck;
  for (int p = threadIdx.x; p < nbuck; p += 256) cur[p] = bstart[p] + gh[p];
  __syncthreads();
  int s = blockIdx.x * chunk;
  int t = min(s + chunk, e);
  for (int i = s + threadIdx.x; i < t; i += 256) {
    int c = col[i];
    int pos = atomicAdd(&cur[c >> BUCK_SHIFT], 1);
    bcol[pos] = c;
    brow[pos] = row[i];
  }
}

// per-bucket exact counting sort in LDS -> rowptr, dis, srcidx
__global__ __launch_bounds__(256) void k_bsort(const int* __restrict__ bcol,
                                               const int* __restrict__ brow,
                                               const int* __restrict__ bstart,
                                               int* __restrict__ rowptr,
                                               float* __restrict__ dis,
                                               int* __restrict__ srcidx, int n) {
  __shared__ int cnt[64];
  __shared__ int pos[64];
  __shared__ int sbs, sbe;
  int tid = threadIdx.x;
  int p = blockIdx.x;
  if (tid < 64) cnt[tid] = 0;
  if (tid == 0) { sbs = bstart[p]; sbe = bstart[p + 1]; }
  __syncthreads();
  int bs = sbs, be = sbe;
  for (int i = bs + tid; i < be; i += 256)
    atomicAdd(&cnt[bcol[i] & 63], 1);
  __syncthreads();
  if (tid < 64) {
    int v = cnt[tid];
    int run = v;
#pragma unroll
    for (int off = 1; off < 64; off <<= 1) {
      int o = __shfl_up(run, off, 64);
      if (tid >= off) run += o;
    }
    int excl = run - v;
    pos[tid] = excl;
    int node = (p << BUCK_SHIFT) + tid;
    if (node < n) {
      rowptr[node] = bs + excl;
      dis[node] = rsqrtf((float)(v + 1));  // +1 self loop
    }
  }
  __syncthreads();
  for (int i = bs + tid; i < be; i += 256) {
    int c = bcol[i];
    int q = atomicAdd(&pos[c & 63], 1);
    srcidx[bs + q] = brow[i];
  }
}

// ---------------- weight pack: WB[n][k] = W[k][n] in bf16 ----------------

__global__ void k_wpack(const float* __restrict__ W1, const float* __restrict__ W2,
                        ushort_t* __restrict__ WB1, ushort_t* __restrict__ WB2) {
  int idx = blockIdx.x * 256 + threadIdx.x;
  if (idx < 128 * 128) {
    int nn = idx >> 7, k = idx & 127;
    WB1[idx] = f2bf(W1[k * HID_C + nn]);
  }
  int idx2 = idx - 128 * 128;
  if (idx2 >= 0 && idx2 < 64 * 128) {
    int nn = idx2 >> 7, k = idx2 & 127;
    WB2[idx2] = f2bf(W2[k * OUT_C + nn]);
  }
}

// ------- GEMM1 (MFMA bf16): h1 = bf16(x @ W1), [N,128]x[128,128] -------

__global__ __launch_bounds__(256) void k_gemm1_mfma(const float* __restrict__ x,
                                                    const ushort_t* __restrict__ WB,
                                                    ushort_t* __restrict__ h1, int n) {
  int wave = threadIdx.x >> 6;
  int lane = threadIdx.x & 63;
  int m = lane & 15;
  int kg = lane >> 4;
  int rowbase = blockIdx.x * 64 + wave * 16;
  int rrow = rowbase + m; if (rrow >= n) rrow = n - 1;
  const float* xrow = x + (size_t)rrow * IN_C + kg * 8;
  f32x4 acc[8] = {};
#pragma unroll
  for (int ks = 0; ks < 4; ks++) {
    float4 a0 = *reinterpret_cast<const float4*>(xrow + ks * 32);
    float4 a1 = *reinterpret_cast<const float4*>(xrow + ks * 32 + 4);
    bf16x8 a;
    a[0] = (short)f2bf(a0.x); a[1] = (short)f2bf(a0.y);
    a[2] = (short)f2bf(a0.z); a[3] = (short)f2bf(a0.w);
    a[4] = (short)f2bf(a1.x); a[5] = (short)f2bf(a1.y);
    a[6] = (short)f2bf(a1.z); a[7] = (short)f2bf(a1.w);
#pragma unroll
    for (int nt = 0; nt < 8; nt++) {
      bf16x8 b = *reinterpret_cast<const bf16x8*>(WB + (nt * 16 + m) * 128 + ks * 32 + kg * 8);
      acc[nt] = __builtin_amdgcn_mfma_f32_16x16x32_bf16(a, b, acc[nt], 0, 0, 0);
    }
  }
#pragma unroll
  for (int nt = 0; nt < 8; nt++)
#pragma unroll
    for (int r = 0; r < 4; r++) {
      int rowi = rowbase + kg * 4 + r;
      if (rowi < n) h1[(size_t)rowi * HID_C + nt * 16 + m] = f2bf(acc[nt][r]);
    }
}

// ------- GEMM2 (MFMA bf16, BN+ReLU fused on A-load) -------

__global__ __launch_bounds__(256) void k_gemm2_mfma(const float* __restrict__ agg,
                                                    const ushort_t* __restrict__ WB,
                                                    const float* __restrict__ bnp,
                                                    ushort_t* __restrict__ h2, int n) {
  int wave = threadIdx.x >> 6;
  int lane = threadIdx.x & 63;
  int m = lane & 15;
  int kg = lane >> 4;
  int rowbase = blockIdx.x * 64 + wave * 16;
  int rrow = rowbase + m; if (rrow >= n) rrow = n - 1;
  const float* arow = agg + (size_t)rrow * HID_C + kg * 8;
  f32x4 acc[4] = {};
#pragma unroll
  for (int ks = 0; ks < 4; ks++) {
    int kbase = ks * 32 + kg * 8;
    float4 a0 = *reinterpret_cast<const float4*>(arow + ks * 32);
    float4 a1 = *reinterpret_cast<const float4*>(arow + ks * 32 + 4);
    float4 s0 = *reinterpret_cast<const float4*>(bnp + kbase);
    float4 s1 = *reinterpret_cast<const float4*>(bnp + kbase + 4);
    float4 t0 = *reinterpret_cast<const float4*>(bnp + 128 + kbase);
    float4 t1 = *reinterpret_cast<const float4*>(bnp + 128 + kbase + 4);
    float v[8];
    v[0] = a0.x * s0.x + t0.x; v[1] = a0.y * s0.y + t0.y;
    v[2] = a0.z * s0.z + t0.z; v[3] = a0.w * s0.w + t0.w;
    v[4] = a1.x * s1.x + t1.x; v[5] = a1.y * s1.y + t1.y;
    v[6] = a1.z * s1.z + t1.z; v[7] = a1.w * s1.w + t1.w;
    bf16x8 a;
#pragma unroll
    for (int q = 0; q < 8; q++) a[q] = (short)f2bf(v[q] > 0.f ? v[q] : 0.f);
#pragma unroll
    for (int nt = 0; nt < 4; nt++) {
      bf16x8 b = *reinterpret_cast<const bf16x8*>(WB + (nt * 16 + m) * 128 + ks * 32 + kg * 8);
      acc[nt] = __builtin_amdgcn_mfma_f32_16x16x32_bf16(a, b, acc[nt], 0, 0, 0);
    }
  }
#pragma unroll
  for (int nt = 0; nt < 4; nt++)
#pragma unroll
    for (int r = 0; r < 4; r++) {
      int rowi = rowbase + kg * 4 + r;
      if (rowi < n) h2[(size_t)rowi * OUT_C + nt * 16 + m] = f2bf(acc[nt][r]);
    }
}

// ------- SpMM (bf16 gather): out_i = di*(di*h_i + sum_j dj*h_j) + bias -------

template <int C>
__global__ __launch_bounds__(256) void k_spmm_bf(const ushort_t* __restrict__ h,
                                                 const float* __restrict__ dis,
                                                 const int* __restrict__ rowptr,
                                                 const int* __restrict__ srcidx,
                                                 const float* __restrict__ bias,
                                                 float* __restrict__ outp, int n) {
  constexpr int LPR = C / 8;
  constexpr int ROWS = 256 / LPR;
  int tid = threadIdx.x;
  int lane = tid & (LPR - 1);
  int r = tid / LPR;
  int i = blockIdx.x * ROWS + r;
  if (i >= n) return;
  int c8 = lane * 8;
  const ushort_t* hb = h + c8;

  float di = dis[i];
  float acc[8];
  u16x8 hv = *reinterpret_cast<const u16x8*>(hb + (size_t)i * C);
#pragma unroll
  for (int q = 0; q < 8; q++) acc[q] = di * bf2f(hv[q]);

  int s = rowptr[i], t = rowptr[i + 1];
  int p = s;
  for (; p + 8 <= t; p += 8) {
    int j[8]; float dj[8]; u16x8 v[8];
#pragma unroll
    for (int k = 0; k < 8; k++) j[k] = srcidx[p + k];
#pragma unroll
    for (int k = 0; k < 8; k++) dj[k] = dis[j[k]];
#pragma unroll
    for (int k = 0; k < 8; k++)
      v[k] = *reinterpret_cast<const u16x8*>(hb + (size_t)j[k] * C);
#pragma unroll
    for (int k = 0; k < 8; k++)
#pragma unroll
      for (int q = 0; q < 8; q++) acc[q] += dj[k] * bf2f(v[k][q]);
  }
  for (; p < t; p++) {
    int j = srcidx[p];
    float dj = dis[j];
    u16x8 v = *reinterpret_cast<const u16x8*>(hb + (size_t)j * C);
#pragma unroll
    for (int q = 0; q < 8; q++) acc[q] += dj * bf2f(v[q]);
  }

  float4 b0 = *reinterpret_cast<const float4*>(bias + c8);
  float4 b1v = *reinterpret_cast<const float4*>(bias + c8 + 4);
  float4 o0, o1;
  o0.x = di * acc[0] + b0.x;  o0.y = di * acc[1] + b0.y;
  o0.z = di * acc[2] + b0.z;  o0.w = di * acc[3] + b0.w;
  o1.x = di * acc[4] + b1v.x; o1.y = di * acc[5] + b1v.y;
  o1.z = di * acc[6] + b1v.z; o1.w = di * acc[7] + b1v.w;
  float* op = outp + (size_t)i * C + c8;
  *reinterpret_cast<float4*>(op) = o0;
  *reinterpret_cast<float4*>(op + 4) = o1;
}

// ---------------- BN stats ----------------

__global__ __launch_bounds__(256) void k_bnstats(const float* __restrict__ agg,
                                                 float* __restrict__ stats, int n) {
  __shared__ float ls[256], lq[256];
  int tid = threadIdx.x;
  int c = tid & 127;
  int half = tid >> 7;
  float s = 0.f, q = 0.f;
  for (int rowi = blockIdx.x * 2 + half; rowi < n; rowi += gridDim.x * 2) {
    float v = agg[(size_t)rowi * HID_C + c];
    s += v;
    q += v * v;
  }
  ls[tid] = s; lq[tid] = q;
  __syncthreads();
  if (tid < 128) {
    s = ls[tid] + ls[tid + 128];
    q = lq[tid] + lq[tid + 128];
    atomicAdd(&stats[tid], s);
    atomicAdd(&stats[128 + tid], q);
  }
}

__global__ void k_bnfinal(const float* __restrict__ stats, const float* __restrict__ gamma,
                          const float* __restrict__ beta, float* __restrict__ bnp, int n) {
  int c = threadIdx.x;
  if (c < 128) {
    float inv_n = 1.f / (float)n;
    float mean = stats[c] * inv_n;
    float var = stats[128 + c] * inv_n - mean * mean;
    float istd = rsqrtf(var + BN_EPS);
    float sc = gamma[c] * istd;
    bnp[c] = sc;
    bnp[128 + c] = beta[c] - mean * sc;
  }
}

// ---------------- launch ----------------

extern "C" void kernel_launch(void* const* d_in, const int* in_sizes, int n_in,
                              void* d_out, int out_size, void* d_ws, size_t ws_size,
                              hipStream_t stream) {
  const float* x     = (const float*)d_in[0];
  const int*   edge  = (const int*)d_in[1];
  const float* W1    = (const float*)d_in[2];
  const float* b1    = (const float*)d_in[3];
  const float* gamma = (const float*)d_in[4];
  const float* beta  = (const float*)d_in[5];
  const float* W2    = (const float*)d_in[6];
  const float* b2    = (const float*)d_in[7];
  float* out = (float*)d_out;

  int n = in_sizes[0] / IN_C;
  int e = in_sizes[1] / 2;
  int n64 = ((n + 63) / 64) * 64;
  int nbuck = (n + 63) >> BUCK_SHIFT;
  const int* row = edge;      // edge_index[0] = source j
  const int* col = edge + e;  // edge_index[1] = target i

  char* ws = (char*)d_ws;
  size_t off = 0;
  auto alloc = [&](size_t bytes) {
    void* p = ws + off;
    off = (off + bytes + 255) & ~(size_t)255;
    return p;
  };
  // persistent
  float*    dis   = (float*)alloc((size_t)n * 4);
  int*      rowp  = (int*)alloc((size_t)(n + 1) * 4);
  int*      srci  = (int*)alloc((size_t)e * 4);
  ushort_t* WB1   = (ushort_t*)alloc(128 * 128 * 2);
  ushort_t* WB2   = (ushort_t*)alloc(64 * 128 * 2);
  ushort_t* h1b   = (ushort_t*)alloc((size_t)n64 * HID_C * 2);
  float*    agg   = (float*)alloc((size_t)n * HID_C * 4);
  ushort_t* h2b   = (ushort_t*)alloc((size_t)n64 * OUT_C * 2);
  float*    stats = (float*)alloc(256 * 4);
  float*    bnp   = (float*)alloc(256 * 4);
  // transients overlay agg (dead before spmm1 fully overwrites agg)
  char* tr = (char*)agg;
  int* bcol   = (int*)tr;                                tr += (size_t)e * 4;
  int* brow   = (int*)tr;                                tr += (size_t)e * 4;
  int* ghist  = (int*)tr;                                tr += (size_t)256 * nbuck * 4;
  int* btotal = (int*)tr;                                tr += (size_t)(nbuck + 1) * 4;
  int* bstart = (int*)tr;
  (void)ws_size; (void)n_in; (void)out_size;

  int chunk = (e + 255) / 256;
  int nb64 = n64 / 64;

  k_init   <<<1, 256, 0, stream>>>(stats);
  k_hist   <<<256, 256, 0, stream>>>(col, ghist, e, nbuck, chunk);
  k_s1     <<<(nbuck + 255) / 256, 256, 0, stream>>>(ghist, btotal, 256, nbuck);
  k_s2     <<<1, 512, 0, stream>>>(btotal, bstart, nbuck, e, rowp, n);
  k_scatter<<<256, 256, 0, stream>>>(row, col, ghist, bstart, bcol, brow, e, nbuck, chunk);
  k_bsort  <<<nbuck, 256, 0, stream>>>(bcol, brow, bstart, rowp, dis, srci, n);
  k_wpack  <<<96, 256, 0, stream>>>(W1, W2, WB1, WB2);
  k_gemm1_mfma<<<nb64, 256, 0, stream>>>(x, WB1, h1b, n);
  k_spmm_bf<HID_C><<<(n + 15) / 16, 256, 0, stream>>>(h1b, dis, rowp, srci, b1, agg, n);
  k_bnstats<<<512, 256, 0, stream>>>(agg, stats, n);
  k_bnfinal<<<1, 128, 0, stream>>>(stats, gamma, beta, bnp, n);
  k_gemm2_mfma<<<nb64, 256, 0, stream>>>(agg, WB2, bnp, h2b, n);
  k_spmm_bf<OUT_C><<<(n + 31) / 32, 256, 0, stream>>>(h2b, dis, rowp, srci, b2, out, n);
}

// Round 5
// 303.605 us; speedup vs baseline: 2.6566x; 1.1561x over previous
//
#include <hip/hip_runtime.h>

#define IN_C 128
#define HID_C 128
#define OUT_C 64
#define BN_EPS 1e-5f
#define BUCK_SHIFT 6            // 64 nodes per bucket
#define MAXBUCK 2048            // supports n up to 131071 (17-bit row id in pack)

typedef unsigned short ushort_t;
typedef __attribute__((ext_vector_type(8))) short bf16x8;
typedef __attribute__((ext_vector_type(4))) float f32x4;
typedef __attribute__((ext_vector_type(8))) unsigned short u16x8;

__device__ __forceinline__ float bf2f(ushort_t u) {
  union { unsigned i; float f; } c; c.i = (unsigned)u << 16; return c.f;
}
__device__ __forceinline__ ushort_t f2bf(float f) {
  union { float f; unsigned u; } c; c.f = f;
  unsigned r = c.u + 0x7FFF + ((c.u >> 16) & 1);
  return (ushort_t)(r >> 16);
}

// ---------------- CSR build via bucket counting sort (no global atomics) ----

__global__ __launch_bounds__(256) void k_hist(const int* __restrict__ col,
                                              int* __restrict__ ghist,
                                              int e, int nbuck, int chunk) {
  __shared__ int h[MAXBUCK];
  for (int p = threadIdx.x; p < nbuck; p += 256) h[p] = 0;
  __syncthreads();
  int s = blockIdx.x * chunk;
  int t = min(s + chunk, e);
  for (int i = s + threadIdx.x; i < t; i += 256)
    atomicAdd(&h[col[i] >> BUCK_SHIFT], 1);
  __syncthreads();
  int* gh = ghist + (size_t)blockIdx.x * nbuck;
  for (int p = threadIdx.x; p < nbuck; p += 256) gh[p] = h[p];
}

// per-bucket exclusive scan across blocks (reads coalesced across threads)
__global__ __launch_bounds__(256) void k_s1(int* __restrict__ ghist,
                                            int* __restrict__ btotal,
                                            int nb, int nbuck) {
  int p = blockIdx.x * 256 + threadIdx.x;
  if (p >= nbuck) return;
  int run = 0;
  for (int b = 0; b < nb; b++) {
    int idx = b * nbuck + p;
    int v = ghist[idx];
    ghist[idx] = run;
    run += v;
  }
  btotal[p] = run;
}

__global__ __launch_bounds__(512) void k_s2(const int* __restrict__ btotal,
                                            int* __restrict__ bstart,
                                            int nbuck, int e,
                                            int* __restrict__ rowptr, int n) {
  __shared__ int sd[512];
  int tid = threadIdx.x;
  int base = tid * 4;
  int v[4]; int s = 0;
#pragma unroll
  for (int q = 0; q < 4; q++) {
    int i = base + q;
    v[q] = (i < nbuck) ? btotal[i] : 0;
    s += v[q];
  }
  sd[tid] = s;
  __syncthreads();
  for (int off = 1; off < 512; off <<= 1) {
    int t = (tid >= off) ? sd[tid - off] : 0;
    __syncthreads();
    sd[tid] += t;
    __syncthreads();
  }
  int run = sd[tid] - s;  // exclusive
#pragma unroll
  for (int q = 0; q < 4; q++) {
    int i = base + q;
    if (i < nbuck) bstart[i] = run;
    run += v[q];
  }
  if (tid == 0) { bstart[nbuck] = e; rowptr[n] = e; }
}

// scatter packed (col&63)<<17 | row into bucket streams (single 4B store/edge)
__global__ __launch_bounds__(256) void k_scatter(const int* __restrict__ row,
                                                 const int* __restrict__ col,
                                                 const int* __restrict__ ghist,
                                                 const int* __restrict__ bstart,
                                                 unsigned* __restrict__ bpack,
                                                 int e, int nbuck, int chunk) {
  __shared__ int cur[MAXBUCK];
  const int* gh = ghist + (size_t)blockIdx.x * nbuck;
  for (int p = threadIdx.x; p < nbuck; p += 256) cur[p] = bstart[p] + gh[p];
  __syncthreads();
  int s = blockIdx.x * chunk;
  int t = min(s + chunk, e);
  for (int i = s + threadIdx.x; i < t; i += 256) {
    int c = col[i];
    int pos = atomicAdd(&cur[c >> BUCK_SHIFT], 1);
    bpack[pos] = ((unsigned)(c & 63) << 17) | (unsigned)row[i];
  }
}

// per-bucket exact counting sort in LDS -> rowptr, dis, srcidx
__global__ __launch_bounds__(256) void k_bsort(const unsigned* __restrict__ bpack,
                                               const int* __restrict__ bstart,
                                               int* __restrict__ rowptr,
                                               float* __restrict__ dis,
                                               int* __restrict__ srcidx, int n) {
  __shared__ int cnt[64];
  __shared__ int pos[64];
  __shared__ int sbs, sbe;
  int tid = threadIdx.x;
  int p = blockIdx.x;
  if (tid < 64) cnt[tid] = 0;
  if (tid == 0) { sbs = bstart[p]; sbe = bstart[p + 1]; }
  __syncthreads();
  int bs = sbs, be = sbe;
  for (int i = bs + tid; i < be; i += 256)
    atomicAdd(&cnt[bpack[i] >> 17], 1);
  __syncthreads();
  if (tid < 64) {
    int v = cnt[tid];
    int run = v;
#pragma unroll
    for (int off = 1; off < 64; off <<= 1) {
      int o = __shfl_up(run, off, 64);
      if (tid >= off) run += o;
    }
    int excl = run - v;
    pos[tid] = excl;
    int node = (p << BUCK_SHIFT) + tid;
    if (node < n) {
      rowptr[node] = bs + excl;
      dis[node] = rsqrtf((float)(v + 1));  // +1 self loop
    }
  }
  __syncthreads();
  for (int i = bs + tid; i < be; i += 256) {
    unsigned v = bpack[i];
    int q = atomicAdd(&pos[v >> 17], 1);
    srcidx[bs + q] = (int)(v & 0x1FFFFu);
  }
}

// ------- weight pack: WB[n][k] = W[k][n] in bf16; also zero stats -------

__global__ void k_wpack(const float* __restrict__ W1, const float* __restrict__ W2,
                        ushort_t* __restrict__ WB1, ushort_t* __restrict__ WB2,
                        float* __restrict__ stats) {
  int idx = blockIdx.x * 256 + threadIdx.x;
  if (blockIdx.x == 0) stats[threadIdx.x] = 0.f;
  if (idx < 128 * 128) {
    int nn = idx >> 7, k = idx & 127;
    WB1[idx] = f2bf(W1[k * HID_C + nn]);
  }
  int idx2 = idx - 128 * 128;
  if (idx2 >= 0 && idx2 < 64 * 128) {
    int nn = idx2 >> 7, k = idx2 & 127;
    WB2[idx2] = f2bf(W2[k * OUT_C + nn]);
  }
}

// ------- GEMM1 (MFMA bf16): h1 = bf16(x @ W1) -------

__global__ __launch_bounds__(256) void k_gemm1_mfma(const float* __restrict__ x,
                                                    const ushort_t* __restrict__ WB,
                                                    ushort_t* __restrict__ h1, int n) {
  int wave = threadIdx.x >> 6;
  int lane = threadIdx.x & 63;
  int m = lane & 15;
  int kg = lane >> 4;
  int rowbase = blockIdx.x * 64 + wave * 16;
  int rrow = rowbase + m; if (rrow >= n) rrow = n - 1;
  const float* xrow = x + (size_t)rrow * IN_C + kg * 8;
  f32x4 acc[8] = {};
#pragma unroll
  for (int ks = 0; ks < 4; ks++) {
    float4 a0 = *reinterpret_cast<const float4*>(xrow + ks * 32);
    float4 a1 = *reinterpret_cast<const float4*>(xrow + ks * 32 + 4);
    bf16x8 a;
    a[0] = (short)f2bf(a0.x); a[1] = (short)f2bf(a0.y);
    a[2] = (short)f2bf(a0.z); a[3] = (short)f2bf(a0.w);
    a[4] = (short)f2bf(a1.x); a[5] = (short)f2bf(a1.y);
    a[6] = (short)f2bf(a1.z); a[7] = (short)f2bf(a1.w);
#pragma unroll
    for (int nt = 0; nt < 8; nt++) {
      bf16x8 b = *reinterpret_cast<const bf16x8*>(WB + (nt * 16 + m) * 128 + ks * 32 + kg * 8);
      acc[nt] = __builtin_amdgcn_mfma_f32_16x16x32_bf16(a, b, acc[nt], 0, 0, 0);
    }
  }
#pragma unroll
  for (int nt = 0; nt < 8; nt++)
#pragma unroll
    for (int r = 0; r < 4; r++) {
      int rowi = rowbase + kg * 4 + r;
      if (rowi < n) h1[(size_t)rowi * HID_C + nt * 16 + m] = f2bf(acc[nt][r]);
    }
}

// ------- GEMM2 (MFMA bf16, BN+ReLU fused on bf16 A-load) -------

__global__ __launch_bounds__(256) void k_gemm2_mfma(const ushort_t* __restrict__ aggb,
                                                    const ushort_t* __restrict__ WB,
                                                    const float* __restrict__ bnp,
                                                    ushort_t* __restrict__ h2, int n) {
  int wave = threadIdx.x >> 6;
  int lane = threadIdx.x & 63;
  int m = lane & 15;
  int kg = lane >> 4;
  int rowbase = blockIdx.x * 64 + wave * 16;
  int rrow = rowbase + m; if (rrow >= n) rrow = n - 1;
  const ushort_t* arow = aggb + (size_t)rrow * HID_C + kg * 8;
  f32x4 acc[4] = {};
#pragma unroll
  for (int ks = 0; ks < 4; ks++) {
    int kbase = ks * 32 + kg * 8;
    u16x8 av = *reinterpret_cast<const u16x8*>(arow + ks * 32);
    float4 s0 = *reinterpret_cast<const float4*>(bnp + kbase);
    float4 s1 = *reinterpret_cast<const float4*>(bnp + kbase + 4);
    float4 t0 = *reinterpret_cast<const float4*>(bnp + 128 + kbase);
    float4 t1 = *reinterpret_cast<const float4*>(bnp + 128 + kbase + 4);
    float v[8];
    v[0] = bf2f(av[0]) * s0.x + t0.x; v[1] = bf2f(av[1]) * s0.y + t0.y;
    v[2] = bf2f(av[2]) * s0.z + t0.z; v[3] = bf2f(av[3]) * s0.w + t0.w;
    v[4] = bf2f(av[4]) * s1.x + t1.x; v[5] = bf2f(av[5]) * s1.y + t1.y;
    v[6] = bf2f(av[6]) * s1.z + t1.z; v[7] = bf2f(av[7]) * s1.w + t1.w;
    bf16x8 a;
#pragma unroll
    for (int q = 0; q < 8; q++) a[q] = (short)f2bf(v[q] > 0.f ? v[q] : 0.f);
#pragma unroll
    for (int nt = 0; nt < 4; nt++) {
      bf16x8 b = *reinterpret_cast<const bf16x8*>(WB + (nt * 16 + m) * 128 + ks * 32 + kg * 8);
      acc[nt] = __builtin_amdgcn_mfma_f32_16x16x32_bf16(a, b, acc[nt], 0, 0, 0);
    }
  }
#pragma unroll
  for (int nt = 0; nt < 4; nt++)
#pragma unroll
    for (int r = 0; r < 4; r++) {
      int rowi = rowbase + kg * 4 + r;
      if (rowi < n) h2[(size_t)rowi * OUT_C + nt * 16 + m] = f2bf(acc[nt][r]);
    }
}

// ------- SpMM (bf16 gather) -> bf16 out: aggb = bf16(di*(di*h_i + sum dj*h_j) + b) -------

__global__ __launch_bounds__(256) void k_spmm1_bf(const ushort_t* __restrict__ h,
                                                  const float* __restrict__ dis,
                                                  const int* __restrict__ rowptr,
                                                  const int* __restrict__ srcidx,
                                                  const float* __restrict__ bias,
                                                  ushort_t* __restrict__ outp, int n) {
  constexpr int C = HID_C;
  constexpr int LPR = C / 8;       // 16 lanes per row
  constexpr int ROWS = 256 / LPR;  // 16 rows per block
  int tid = threadIdx.x;
  int lane = tid & (LPR - 1);
  int r = tid / LPR;
  int i = blockIdx.x * ROWS + r;
  if (i >= n) return;
  int c8 = lane * 8;
  const ushort_t* hb = h + c8;

  float di = dis[i];
  float acc[8];
  u16x8 hv = *reinterpret_cast<const u16x8*>(hb + (size_t)i * C);
#pragma unroll
  for (int q = 0; q < 8; q++) acc[q] = di * bf2f(hv[q]);

  int s = rowptr[i], t = rowptr[i + 1];
  int p = s;
  for (; p + 8 <= t; p += 8) {
    int j[8]; float dj[8]; u16x8 v[8];
#pragma unroll
    for (int k = 0; k < 8; k++) j[k] = srcidx[p + k];
#pragma unroll
    for (int k = 0; k < 8; k++) dj[k] = dis[j[k]];
#pragma unroll
    for (int k = 0; k < 8; k++)
      v[k] = *reinterpret_cast<const u16x8*>(hb + (size_t)j[k] * C);
#pragma unroll
    for (int k = 0; k < 8; k++)
#pragma unroll
      for (int q = 0; q < 8; q++) acc[q] += dj[k] * bf2f(v[k][q]);
  }
  for (; p < t; p++) {
    int j = srcidx[p];
    float dj = dis[j];
    u16x8 v = *reinterpret_cast<const u16x8*>(hb + (size_t)j * C);
#pragma unroll
    for (int q = 0; q < 8; q++) acc[q] += dj * bf2f(v[q]);
  }

  float4 b0 = *reinterpret_cast<const float4*>(bias + c8);
  float4 b1v = *reinterpret_cast<const float4*>(bias + c8 + 4);
  u16x8 o;
  o[0] = f2bf(di * acc[0] + b0.x);  o[1] = f2bf(di * acc[1] + b0.y);
  o[2] = f2bf(di * acc[2] + b0.z);  o[3] = f2bf(di * acc[3] + b0.w);
  o[4] = f2bf(di * acc[4] + b1v.x); o[5] = f2bf(di * acc[5] + b1v.y);
  o[6] = f2bf(di * acc[6] + b1v.z); o[7] = f2bf(di * acc[7] + b1v.w);
  *reinterpret_cast<u16x8*>(outp + (size_t)i * C + c8) = o;
}

// ------- SpMM2 (bf16 gather, 64ch) -> fp32 out -------

__global__ __launch_bounds__(256) void k_spmm2_bf(const ushort_t* __restrict__ h,
                                                  const float* __restrict__ dis,
                                                  const int* __restrict__ rowptr,
                                                  const int* __restrict__ srcidx,
                                                  const float* __restrict__ bias,
                                                  float* __restrict__ outp, int n) {
  constexpr int C = OUT_C;
  constexpr int LPR = C / 8;       // 8
  constexpr int ROWS = 256 / LPR;  // 32
  int tid = threadIdx.x;
  int lane = tid & (LPR - 1);
  int r = tid / LPR;
  int i = blockIdx.x * ROWS + r;
  if (i >= n) return;
  int c8 = lane * 8;
  const ushort_t* hb = h + c8;

  float di = dis[i];
  float acc[8];
  u16x8 hv = *reinterpret_cast<const u16x8*>(hb + (size_t)i * C);
#pragma unroll
  for (int q = 0; q < 8; q++) acc[q] = di * bf2f(hv[q]);

  int s = rowptr[i], t = rowptr[i + 1];
  int p = s;
  for (; p + 8 <= t; p += 8) {
    int j[8]; float dj[8]; u16x8 v[8];
#pragma unroll
    for (int k = 0; k < 8; k++) j[k] = srcidx[p + k];
#pragma unroll
    for (int k = 0; k < 8; k++) dj[k] = dis[j[k]];
#pragma unroll
    for (int k = 0; k < 8; k++)
      v[k] = *reinterpret_cast<const u16x8*>(hb + (size_t)j[k] * C);
#pragma unroll
    for (int k = 0; k < 8; k++)
#pragma unroll
      for (int q = 0; q < 8; q++) acc[q] += dj[k] * bf2f(v[k][q]);
  }
  for (; p < t; p++) {
    int j = srcidx[p];
    float dj = dis[j];
    u16x8 v = *reinterpret_cast<const u16x8*>(hb + (size_t)j * C);
#pragma unroll
    for (int q = 0; q < 8; q++) acc[q] += dj * bf2f(v[q]);
  }

  float4 b0 = *reinterpret_cast<const float4*>(bias + c8);
  float4 b1v = *reinterpret_cast<const float4*>(bias + c8 + 4);
  float4 o0, o1;
  o0.x = di * acc[0] + b0.x;  o0.y = di * acc[1] + b0.y;
  o0.z = di * acc[2] + b0.z;  o0.w = di * acc[3] + b0.w;
  o1.x = di * acc[4] + b1v.x; o1.y = di * acc[5] + b1v.y;
  o1.z = di * acc[6] + b1v.z; o1.w = di * acc[7] + b1v.w;
  float* op = outp + (size_t)i * C + c8;
  *reinterpret_cast<float4*>(op) = o0;
  *reinterpret_cast<float4*>(op + 4) = o1;
}

// ---------------- BN stats over bf16 agg (vectorized) ----------------

__global__ __launch_bounds__(256) void k_bnstats(const ushort_t* __restrict__ aggb,
                                                 float* __restrict__ stats, int n) {
  __shared__ float lsum[256 * 8];
  __shared__ float lsq[256 * 8];
  int tid = threadIdx.x;
  int lane = tid & 15;          // channel-octet
  int rg = tid >> 4;            // row-in-group 0..15
  float s[8] = {}, q[8] = {};
  for (int row = blockIdx.x * 16 + rg; row < n; row += gridDim.x * 16) {
    u16x8 v = *reinterpret_cast<const u16x8*>(aggb + (size_t)row * HID_C + lane * 8);
#pragma unroll
    for (int k = 0; k < 8; k++) {
      float f = bf2f(v[k]);
      s[k] += f;
      q[k] += f * f;
    }
  }
#pragma unroll
  for (int k = 0; k < 8; k++) { lsum[tid * 8 + k] = s[k]; lsq[tid * 8 + k] = q[k]; }
  __syncthreads();
  if (tid < 128) {
    int ln = tid >> 3, k = tid & 7;   // channel c = ln*8+k
    float ss = 0.f, qq = 0.f;
    for (int r = 0; r < 16; r++) {
      int idx = ((r << 4) + ln) * 8 + k;
      ss += lsum[idx];
      qq += lsq[idx];
    }
    atomicAdd(&stats[tid], ss);
    atomicAdd(&stats[128 + tid], qq);
  }
}

__global__ void k_bnfinal(const float* __restrict__ stats, const float* __restrict__ gamma,
                          const float* __restrict__ beta, float* __restrict__ bnp, int n) {
  int c = threadIdx.x;
  if (c < 128) {
    float inv_n = 1.f / (float)n;
    float mean = stats[c] * inv_n;
    float var = stats[128 + c] * inv_n - mean * mean;
    float istd = rsqrtf(var + BN_EPS);
    float sc = gamma[c] * istd;
    bnp[c] = sc;
    bnp[128 + c] = beta[c] - mean * sc;
  }
}

// ---------------- launch ----------------

extern "C" void kernel_launch(void* const* d_in, const int* in_sizes, int n_in,
                              void* d_out, int out_size, void* d_ws, size_t ws_size,
                              hipStream_t stream) {
  const float* x     = (const float*)d_in[0];
  const int*   edge  = (const int*)d_in[1];
  const float* W1    = (const float*)d_in[2];
  const float* b1    = (const float*)d_in[3];
  const float* gamma = (const float*)d_in[4];
  const float* beta  = (const float*)d_in[5];
  const float* W2    = (const float*)d_in[6];
  const float* b2    = (const float*)d_in[7];
  float* out = (float*)d_out;

  int n = in_sizes[0] / IN_C;
  int e = in_sizes[1] / 2;
  int n64 = ((n + 63) / 64) * 64;
  int nbuck = (n + 63) >> BUCK_SHIFT;
  const int* row = edge;      // edge_index[0] = source j
  const int* col = edge + e;  // edge_index[1] = target i

  char* ws = (char*)d_ws;
  size_t off = 0;
  auto alloc = [&](size_t bytes) {
    void* p = ws + off;
    off = (off + bytes + 255) & ~(size_t)255;
    return p;
  };
  // persistent
  float*    dis   = (float*)alloc((size_t)n * 4);
  int*      rowp  = (int*)alloc((size_t)(n + 1) * 4);
  int*      srci  = (int*)alloc((size_t)e * 4);
  ushort_t* WB1   = (ushort_t*)alloc(128 * 128 * 2);
  ushort_t* WB2   = (ushort_t*)alloc(64 * 128 * 2);
  ushort_t* h1b   = (ushort_t*)alloc((size_t)n64 * HID_C * 2);
  ushort_t* aggb  = (ushort_t*)alloc((size_t)n64 * HID_C * 2);
  ushort_t* h2b   = (ushort_t*)alloc((size_t)n64 * OUT_C * 2);
  float*    stats = (float*)alloc(256 * 4);
  float*    bnp   = (float*)alloc(256 * 4);
  // transients overlay aggb (dead until spmm1 writes it, after bsort)
  char* tr = (char*)aggb;
  unsigned* bpack = (unsigned*)tr;                       tr += (size_t)e * 4;
  int* ghist  = (int*)tr;                                tr += (size_t)256 * nbuck * 4;
  int* btotal = (int*)tr;                                tr += (size_t)(nbuck + 1) * 4;
  int* bstart = (int*)tr;
  (void)ws_size; (void)n_in; (void)out_size;

  int chunk = (e + 255) / 256;
  int nb64 = n64 / 64;

  k_wpack  <<<96, 256, 0, stream>>>(W1, W2, WB1, WB2, stats);
  k_hist   <<<256, 256, 0, stream>>>(col, ghist, e, nbuck, chunk);
  k_s1     <<<(nbuck + 255) / 256, 256, 0, stream>>>(ghist, btotal, 256, nbuck);
  k_s2     <<<1, 512, 0, stream>>>(btotal, bstart, nbuck, e, rowp, n);
  k_scatter<<<256, 256, 0, stream>>>(row, col, ghist, bstart, bpack, e, nbuck, chunk);
  k_bsort  <<<nbuck, 256, 0, stream>>>(bpack, bstart, rowp, dis, srci, n);
  k_gemm1_mfma<<<nb64, 256, 0, stream>>>(x, WB1, h1b, n);
  k_spmm1_bf<<<(n + 15) / 16, 256, 0, stream>>>(h1b, dis, rowp, srci, b1, aggb, n);
  k_bnstats<<<512, 256, 0, stream>>>(aggb, stats, n);
  k_bnfinal<<<1, 128, 0, stream>>>(stats, gamma, beta, bnp, n);
  k_gemm2_mfma<<<nb64, 256, 0, stream>>>(aggb, WB2, bnp, h2b, n);
  k_spmm2_bf<<<(n + 31) / 32, 256, 0, stream>>>(h2b, dis, rowp, srci, b2, out, n);
}

// Round 6
// 240.212 us; speedup vs baseline: 3.3577x; 1.2639x over previous
//
#include <hip/hip_runtime.h>

#define IN_C 128
#define HID_C 128
#define OUT_C 64
#define BN_EPS 1e-5f
#define BUCK_SHIFT 6            // 64 nodes per bucket
#define MAXBUCK 2048            // supports n up to 131071 (17-bit row id in pack)

typedef unsigned short ushort_t;
typedef __attribute__((ext_vector_type(8))) short bf16x8;
typedef __attribute__((ext_vector_type(4))) float f32x4;
typedef __attribute__((ext_vector_type(8))) unsigned short u16x8;

__device__ __forceinline__ float bf2f(ushort_t u) {
  union { unsigned i; float f; } c; c.i = (unsigned)u << 16; return c.f;
}
__device__ __forceinline__ ushort_t f2bf(float f) {
  union { float f; unsigned u; } c; c.f = f;
  unsigned r = c.u + 0x7FFF + ((c.u >> 16) & 1);
  return (ushort_t)(r >> 16);
}

// ---------------- CSR build via bucket counting sort (no global atomics) ----

__global__ __launch_bounds__(256) void k_hist(const int* __restrict__ col,
                                              int* __restrict__ ghist,
                                              int e, int nbuck, int chunk) {
  __shared__ int h[MAXBUCK];
  for (int p = threadIdx.x; p < nbuck; p += 256) h[p] = 0;
  __syncthreads();
  int s = blockIdx.x * chunk;
  int t = min(s + chunk, e);
  for (int i = s + threadIdx.x; i < t; i += 256)
    atomicAdd(&h[col[i] >> BUCK_SHIFT], 1);
  __syncthreads();
  int* gh = ghist + (size_t)blockIdx.x * nbuck;
  for (int p = threadIdx.x; p < nbuck; p += 256) gh[p] = h[p];
}

// per-bucket exclusive scan across the 256 hist blocks; one block per bucket
__global__ __launch_bounds__(256) void k_s1(int* __restrict__ ghist,
                                            int* __restrict__ btotal, int nbuck) {
  __shared__ int sd[256];
  int p = blockIdx.x;          // bucket
  int tid = threadIdx.x;       // hist block
  int idx = tid * nbuck + p;
  int v = ghist[idx];
  sd[tid] = v;
  __syncthreads();
  for (int off = 1; off < 256; off <<= 1) {
    int t = (tid >= off) ? sd[tid - off] : 0;
    __syncthreads();
    sd[tid] += t;
    __syncthreads();
  }
  ghist[idx] = sd[tid] - v;    // exclusive within bucket
  if (tid == 255) btotal[p] = sd[255];
}

__global__ __launch_bounds__(512) void k_s2(const int* __restrict__ btotal,
                                            int* __restrict__ bstart,
                                            int nbuck, int e,
                                            int* __restrict__ rowptr, int n) {
  __shared__ int sd[512];
  int tid = threadIdx.x;
  int base = tid * 4;
  int v[4]; int s = 0;
#pragma unroll
  for (int q = 0; q < 4; q++) {
    int i = base + q;
    v[q] = (i < nbuck) ? btotal[i] : 0;
    s += v[q];
  }
  sd[tid] = s;
  __syncthreads();
  for (int off = 1; off < 512; off <<= 1) {
    int t = (tid >= off) ? sd[tid - off] : 0;
    __syncthreads();
    sd[tid] += t;
    __syncthreads();
  }
  int run = sd[tid] - s;  // exclusive
#pragma unroll
  for (int q = 0; q < 4; q++) {
    int i = base + q;
    if (i < nbuck) bstart[i] = run;
    run += v[q];
  }
  if (tid == 0) { bstart[nbuck] = e; rowptr[n] = e; }
}

// scatter packed (col&63)<<17 | row into bucket streams (single 4B store/edge)
__global__ __launch_bounds__(256) void k_scatter(const int* __restrict__ row,
                                                 const int* __restrict__ col,
                                                 const int* __restrict__ ghist,
                                                 const int* __restrict__ bstart,
                                                 unsigned* __restrict__ bpack,
                                                 int e, int nbuck, int chunk) {
  __shared__ int cur[MAXBUCK];
  const int* gh = ghist + (size_t)blockIdx.x * nbuck;
  for (int p = threadIdx.x; p < nbuck; p += 256) cur[p] = bstart[p] + gh[p];
  __syncthreads();
  int s = blockIdx.x * chunk;
  int t = min(s + chunk, e);
  for (int i = s + threadIdx.x; i < t; i += 256) {
    int c = col[i];
    int pos = atomicAdd(&cur[c >> BUCK_SHIFT], 1);
    bpack[pos] = ((unsigned)(c & 63) << 17) | (unsigned)row[i];
  }
}

// per-bucket exact counting sort in LDS -> rowptr, dis, srcidx
__global__ __launch_bounds__(256) void k_bsort(const unsigned* __restrict__ bpack,
                                               const int* __restrict__ bstart,
                                               int* __restrict__ rowptr,
                                               float* __restrict__ dis,
                                               int* __restrict__ srcidx, int n) {
  __shared__ int cnt[64];
  __shared__ int pos[64];
  __shared__ int sbs, sbe;
  int tid = threadIdx.x;
  int p = blockIdx.x;
  if (tid < 64) cnt[tid] = 0;
  if (tid == 0) { sbs = bstart[p]; sbe = bstart[p + 1]; }
  __syncthreads();
  int bs = sbs, be = sbe;
  for (int i = bs + tid; i < be; i += 256)
    atomicAdd(&cnt[bpack[i] >> 17], 1);
  __syncthreads();
  if (tid < 64) {
    int v = cnt[tid];
    int run = v;
#pragma unroll
    for (int off = 1; off < 64; off <<= 1) {
      int o = __shfl_up(run, off, 64);
      if (tid >= off) run += o;
    }
    int excl = run - v;
    pos[tid] = excl;
    int node = (p << BUCK_SHIFT) + tid;
    if (node < n) {
      rowptr[node] = bs + excl;
      dis[node] = rsqrtf((float)(v + 1));  // +1 self loop
    }
  }
  __syncthreads();
  for (int i = bs + tid; i < be; i += 256) {
    unsigned v = bpack[i];
    int q = atomicAdd(&pos[v >> 17], 1);
    srcidx[bs + q] = (int)(v & 0x1FFFFu);
  }
}

// ------- weight pack: WB[n][k] = W[k][n] in bf16; also zero stats -------

__global__ void k_wpack(const float* __restrict__ W1, const float* __restrict__ W2,
                        ushort_t* __restrict__ WB1, ushort_t* __restrict__ WB2,
                        float* __restrict__ stats) {
  int idx = blockIdx.x * 256 + threadIdx.x;
  if (blockIdx.x == 0) stats[threadIdx.x] = 0.f;
  if (idx < 128 * 128) {
    int nn = idx >> 7, k = idx & 127;
    WB1[idx] = f2bf(W1[k * HID_C + nn]);
  }
  int idx2 = idx - 128 * 128;
  if (idx2 >= 0 && idx2 < 64 * 128) {
    int nn = idx2 >> 7, k = idx2 & 127;
    WB2[idx2] = f2bf(W2[k * OUT_C + nn]);
  }
}

// ------- GEMM1 (MFMA bf16): h1 = bf16(x @ W1) -------

__global__ __launch_bounds__(256) void k_gemm1_mfma(const float* __restrict__ x,
                                                    const ushort_t* __restrict__ WB,
                                                    ushort_t* __restrict__ h1, int n) {
  int wave = threadIdx.x >> 6;
  int lane = threadIdx.x & 63;
  int m = lane & 15;
  int kg = lane >> 4;
  int rowbase = blockIdx.x * 64 + wave * 16;
  int rrow = rowbase + m; if (rrow >= n) rrow = n - 1;
  const float* xrow = x + (size_t)rrow * IN_C + kg * 8;
  f32x4 acc[8] = {};
#pragma unroll
  for (int ks = 0; ks < 4; ks++) {
    float4 a0 = *reinterpret_cast<const float4*>(xrow + ks * 32);
    float4 a1 = *reinterpret_cast<const float4*>(xrow + ks * 32 + 4);
    bf16x8 a;
    a[0] = (short)f2bf(a0.x); a[1] = (short)f2bf(a0.y);
    a[2] = (short)f2bf(a0.z); a[3] = (short)f2bf(a0.w);
    a[4] = (short)f2bf(a1.x); a[5] = (short)f2bf(a1.y);
    a[6] = (short)f2bf(a1.z); a[7] = (short)f2bf(a1.w);
#pragma unroll
    for (int nt = 0; nt < 8; nt++) {
      bf16x8 b = *reinterpret_cast<const bf16x8*>(WB + (nt * 16 + m) * 128 + ks * 32 + kg * 8);
      acc[nt] = __builtin_amdgcn_mfma_f32_16x16x32_bf16(a, b, acc[nt], 0, 0, 0);
    }
  }
#pragma unroll
  for (int nt = 0; nt < 8; nt++)
#pragma unroll
    for (int r = 0; r < 4; r++) {
      int rowi = rowbase + kg * 4 + r;
      if (rowi < n) h1[(size_t)rowi * HID_C + nt * 16 + m] = f2bf(acc[nt][r]);
    }
}

// ------- GEMM2 (MFMA bf16, BN+ReLU fused on bf16 A-load; BN params from stats) -------

__global__ __launch_bounds__(256) void k_gemm2_mfma(const ushort_t* __restrict__ aggb,
                                                    const ushort_t* __restrict__ WB,
                                                    const float* __restrict__ stats,
                                                    const float* __restrict__ gamma,
                                                    const float* __restrict__ beta,
                                                    ushort_t* __restrict__ h2, int n) {
  __shared__ float bnp_s[256];
  int tid = threadIdx.x;
  if (tid < 128) {
    float inv_n = 1.f / (float)n;
    float mean = stats[tid] * inv_n;
    float var = stats[128 + tid] * inv_n - mean * mean;
    float istd = rsqrtf(var + BN_EPS);
    float sc = gamma[tid] * istd;
    bnp_s[tid] = sc;
    bnp_s[128 + tid] = beta[tid] - mean * sc;
  }
  __syncthreads();
  int wave = tid >> 6;
  int lane = tid & 63;
  int m = lane & 15;
  int kg = lane >> 4;
  int rowbase = blockIdx.x * 64 + wave * 16;
  int rrow = rowbase + m; if (rrow >= n) rrow = n - 1;
  const ushort_t* arow = aggb + (size_t)rrow * HID_C + kg * 8;
  f32x4 acc[4] = {};
#pragma unroll
  for (int ks = 0; ks < 4; ks++) {
    int kbase = ks * 32 + kg * 8;
    u16x8 av = *reinterpret_cast<const u16x8*>(arow + ks * 32);
    float v[8];
#pragma unroll
    for (int q = 0; q < 8; q++)
      v[q] = bf2f(av[q]) * bnp_s[kbase + q] + bnp_s[128 + kbase + q];
    bf16x8 a;
#pragma unroll
    for (int q = 0; q < 8; q++) a[q] = (short)f2bf(v[q] > 0.f ? v[q] : 0.f);
#pragma unroll
    for (int nt = 0; nt < 4; nt++) {
      bf16x8 b = *reinterpret_cast<const bf16x8*>(WB + (nt * 16 + m) * 128 + ks * 32 + kg * 8);
      acc[nt] = __builtin_amdgcn_mfma_f32_16x16x32_bf16(a, b, acc[nt], 0, 0, 0);
    }
  }
#pragma unroll
  for (int nt = 0; nt < 4; nt++)
#pragma unroll
    for (int r = 0; r < 4; r++) {
      int rowi = rowbase + kg * 4 + r;
      if (rowi < n) h2[(size_t)rowi * OUT_C + nt * 16 + m] = f2bf(acc[nt][r]);
    }
}

// ------- SpMM1 (bf16 gather, 16-deep ILP) -> bf16 out -------

__global__ __launch_bounds__(256) void k_spmm1_bf(const ushort_t* __restrict__ h,
                                                  const float* __restrict__ dis,
                                                  const int* __restrict__ rowptr,
                                                  const int* __restrict__ srcidx,
                                                  const float* __restrict__ bias,
                                                  ushort_t* __restrict__ outp, int n) {
  constexpr int C = HID_C;
  constexpr int LPR = C / 8;       // 16 lanes per row
  constexpr int ROWS = 256 / LPR;  // 16 rows per block
  int tid = threadIdx.x;
  int lane = tid & (LPR - 1);
  int r = tid / LPR;
  int i = blockIdx.x * ROWS + r;
  if (i >= n) return;
  int c8 = lane * 8;
  const ushort_t* hb = h + c8;

  float di = dis[i];
  float acc[8];
  u16x8 hv = *reinterpret_cast<const u16x8*>(hb + (size_t)i * C);
#pragma unroll
  for (int q = 0; q < 8; q++) acc[q] = di * bf2f(hv[q]);

  int s = rowptr[i], t = rowptr[i + 1];
  int p = s;
  for (; p + 16 <= t; p += 16) {
    int jA[8], jB[8]; float dA[8], dB[8]; u16x8 vA[8], vB[8];
#pragma unroll
    for (int k = 0; k < 8; k++) jA[k] = srcidx[p + k];
#pragma unroll
    for (int k = 0; k < 8; k++) jB[k] = srcidx[p + 8 + k];
#pragma unroll
    for (int k = 0; k < 8; k++) dA[k] = dis[jA[k]];
#pragma unroll
    for (int k = 0; k < 8; k++) dB[k] = dis[jB[k]];
#pragma unroll
    for (int k = 0; k < 8; k++)
      vA[k] = *reinterpret_cast<const u16x8*>(hb + (size_t)jA[k] * C);
#pragma unroll
    for (int k = 0; k < 8; k++)
      vB[k] = *reinterpret_cast<const u16x8*>(hb + (size_t)jB[k] * C);
#pragma unroll
    for (int k = 0; k < 8; k++)
#pragma unroll
      for (int q = 0; q < 8; q++) acc[q] += dA[k] * bf2f(vA[k][q]);
#pragma unroll
    for (int k = 0; k < 8; k++)
#pragma unroll
      for (int q = 0; q < 8; q++) acc[q] += dB[k] * bf2f(vB[k][q]);
  }
  for (; p + 4 <= t; p += 4) {
    int j[4]; float dj[4]; u16x8 v[4];
#pragma unroll
    for (int k = 0; k < 4; k++) j[k] = srcidx[p + k];
#pragma unroll
    for (int k = 0; k < 4; k++) dj[k] = dis[j[k]];
#pragma unroll
    for (int k = 0; k < 4; k++)
      v[k] = *reinterpret_cast<const u16x8*>(hb + (size_t)j[k] * C);
#pragma unroll
    for (int k = 0; k < 4; k++)
#pragma unroll
      for (int q = 0; q < 8; q++) acc[q] += dj[k] * bf2f(v[k][q]);
  }
  for (; p < t; p++) {
    int j = srcidx[p];
    float dj = dis[j];
    u16x8 v = *reinterpret_cast<const u16x8*>(hb + (size_t)j * C);
#pragma unroll
    for (int q = 0; q < 8; q++) acc[q] += dj * bf2f(v[q]);
  }

  float4 b0 = *reinterpret_cast<const float4*>(bias + c8);
  float4 b1v = *reinterpret_cast<const float4*>(bias + c8 + 4);
  u16x8 o;
  o[0] = f2bf(di * acc[0] + b0.x);  o[1] = f2bf(di * acc[1] + b0.y);
  o[2] = f2bf(di * acc[2] + b0.z);  o[3] = f2bf(di * acc[3] + b0.w);
  o[4] = f2bf(di * acc[4] + b1v.x); o[5] = f2bf(di * acc[5] + b1v.y);
  o[6] = f2bf(di * acc[6] + b1v.z); o[7] = f2bf(di * acc[7] + b1v.w);
  *reinterpret_cast<u16x8*>(outp + (size_t)i * C + c8) = o;
}

// ------- SpMM2 (bf16 gather, 64ch, 16-deep ILP) -> fp32 out -------

__global__ __launch_bounds__(256) void k_spmm2_bf(const ushort_t* __restrict__ h,
                                                  const float* __restrict__ dis,
                                                  const int* __restrict__ rowptr,
                                                  const int* __restrict__ srcidx,
                                                  const float* __restrict__ bias,
                                                  float* __restrict__ outp, int n) {
  constexpr int C = OUT_C;
  constexpr int LPR = C / 8;       // 8
  constexpr int ROWS = 256 / LPR;  // 32
  int tid = threadIdx.x;
  int lane = tid & (LPR - 1);
  int r = tid / LPR;
  int i = blockIdx.x * ROWS + r;
  if (i >= n) return;
  int c8 = lane * 8;
  const ushort_t* hb = h + c8;

  float di = dis[i];
  float acc[8];
  u16x8 hv = *reinterpret_cast<const u16x8*>(hb + (size_t)i * C);
#pragma unroll
  for (int q = 0; q < 8; q++) acc[q] = di * bf2f(hv[q]);

  int s = rowptr[i], t = rowptr[i + 1];
  int p = s;
  for (; p + 16 <= t; p += 16) {
    int jA[8], jB[8]; float dA[8], dB[8]; u16x8 vA[8], vB[8];
#pragma unroll
    for (int k = 0; k < 8; k++) jA[k] = srcidx[p + k];
#pragma unroll
    for (int k = 0; k < 8; k++) jB[k] = srcidx[p + 8 + k];
#pragma unroll
    for (int k = 0; k < 8; k++) dA[k] = dis[jA[k]];
#pragma unroll
    for (int k = 0; k < 8; k++) dB[k] = dis[jB[k]];
#pragma unroll
    for (int k = 0; k < 8; k++)
      vA[k] = *reinterpret_cast<const u16x8*>(hb + (size_t)jA[k] * C);
#pragma unroll
    for (int k = 0; k < 8; k++)
      vB[k] = *reinterpret_cast<const u16x8*>(hb + (size_t)jB[k] * C);
#pragma unroll
    for (int k = 0; k < 8; k++)
#pragma unroll
      for (int q = 0; q < 8; q++) acc[q] += dA[k] * bf2f(vA[k][q]);
#pragma unroll
    for (int k = 0; k < 8; k++)
#pragma unroll
      for (int q = 0; q < 8; q++) acc[q] += dB[k] * bf2f(vB[k][q]);
  }
  for (; p + 4 <= t; p += 4) {
    int j[4]; float dj[4]; u16x8 v[4];
#pragma unroll
    for (int k = 0; k < 4; k++) j[k] = srcidx[p + k];
#pragma unroll
    for (int k = 0; k < 4; k++) dj[k] = dis[j[k]];
#pragma unroll
    for (int k = 0; k < 4; k++)
      v[k] = *reinterpret_cast<const u16x8*>(hb + (size_t)j[k] * C);
#pragma unroll
    for (int k = 0; k < 4; k++)
#pragma unroll
      for (int q = 0; q < 8; q++) acc[q] += dj[k] * bf2f(v[k][q]);
  }
  for (; p < t; p++) {
    int j = srcidx[p];
    float dj = dis[j];
    u16x8 v = *reinterpret_cast<const u16x8*>(hb + (size_t)j * C);
#pragma unroll
    for (int q = 0; q < 8; q++) acc[q] += dj * bf2f(v[q]);
  }

  float4 b0 = *reinterpret_cast<const float4*>(bias + c8);
  float4 b1v = *reinterpret_cast<const float4*>(bias + c8 + 4);
  float4 o0, o1;
  o0.x = di * acc[0] + b0.x;  o0.y = di * acc[1] + b0.y;
  o0.z = di * acc[2] + b0.z;  o0.w = di * acc[3] + b0.w;
  o1.x = di * acc[4] + b1v.x; o1.y = di * acc[5] + b1v.y;
  o1.z = di * acc[6] + b1v.z; o1.w = di * acc[7] + b1v.w;
  float* op = outp + (size_t)i * C + c8;
  *reinterpret_cast<float4*>(op) = o0;
  *reinterpret_cast<float4*>(op + 4) = o1;
}

// ---------------- BN stats over bf16 agg (vectorized) ----------------

__global__ __launch_bounds__(256) void k_bnstats(const ushort_t* __restrict__ aggb,
                                                 float* __restrict__ stats, int n) {
  __shared__ float lsum[256 * 8];
  __shared__ float lsq[256 * 8];
  int tid = threadIdx.x;
  int lane = tid & 15;          // channel-octet
  int rg = tid >> 4;            // row-in-group 0..15
  float s[8] = {}, q[8] = {};
  for (int row = blockIdx.x * 16 + rg; row < n; row += gridDim.x * 16) {
    u16x8 v = *reinterpret_cast<const u16x8*>(aggb + (size_t)row * HID_C + lane * 8);
#pragma unroll
    for (int k = 0; k < 8; k++) {
      float f = bf2f(v[k]);
      s[k] += f;
      q[k] += f * f;
    }
  }
#pragma unroll
  for (int k = 0; k < 8; k++) { lsum[tid * 8 + k] = s[k]; lsq[tid * 8 + k] = q[k]; }
  __syncthreads();
  if (tid < 128) {
    int ln = tid >> 3, k = tid & 7;   // channel c = ln*8+k
    float ss = 0.f, qq = 0.f;
    for (int r = 0; r < 16; r++) {
      int idx = ((r << 4) + ln) * 8 + k;
      ss += lsum[idx];
      qq += lsq[idx];
    }
    atomicAdd(&stats[tid], ss);
    atomicAdd(&stats[128 + tid], qq);
  }
}

// ---------------- launch ----------------

extern "C" void kernel_launch(void* const* d_in, const int* in_sizes, int n_in,
                              void* d_out, int out_size, void* d_ws, size_t ws_size,
                              hipStream_t stream) {
  const float* x     = (const float*)d_in[0];
  const int*   edge  = (const int*)d_in[1];
  const float* W1    = (const float*)d_in[2];
  const float* b1    = (const float*)d_in[3];
  const float* gamma = (const float*)d_in[4];
  const float* beta  = (const float*)d_in[5];
  const float* W2    = (const float*)d_in[6];
  const float* b2    = (const float*)d_in[7];
  float* out = (float*)d_out;

  int n = in_sizes[0] / IN_C;
  int e = in_sizes[1] / 2;
  int n64 = ((n + 63) / 64) * 64;
  int nbuck = (n + 63) >> BUCK_SHIFT;
  const int* row = edge;      // edge_index[0] = source j
  const int* col = edge + e;  // edge_index[1] = target i

  char* ws = (char*)d_ws;
  size_t off = 0;
  auto alloc = [&](size_t bytes) {
    void* p = ws + off;
    off = (off + bytes + 255) & ~(size_t)255;
    return p;
  };
  // persistent
  float*    dis   = (float*)alloc((size_t)n * 4);
  int*      rowp  = (int*)alloc((size_t)(n + 1) * 4);
  int*      srci  = (int*)alloc((size_t)e * 4);
  ushort_t* WB1   = (ushort_t*)alloc(128 * 128 * 2);
  ushort_t* WB2   = (ushort_t*)alloc(64 * 128 * 2);
  ushort_t* h1b   = (ushort_t*)alloc((size_t)n64 * HID_C * 2);
  ushort_t* aggb  = (ushort_t*)alloc((size_t)n64 * HID_C * 2);
  ushort_t* h2b   = (ushort_t*)alloc((size_t)n64 * OUT_C * 2);
  float*    stats = (float*)alloc(256 * 4);
  // transients overlay aggb (dead until spmm1 writes it, after bsort)
  char* tr = (char*)aggb;
  unsigned* bpack = (unsigned*)tr;                       tr += (size_t)e * 4;
  int* ghist  = (int*)tr;                                tr += (size_t)256 * nbuck * 4;
  int* btotal = (int*)tr;                                tr += (size_t)(nbuck + 1) * 4;
  int* bstart = (int*)tr;
  (void)ws_size; (void)n_in; (void)out_size;

  int chunk = (e + 255) / 256;
  int nb64 = n64 / 64;

  k_wpack  <<<96, 256, 0, stream>>>(W1, W2, WB1, WB2, stats);
  k_hist   <<<256, 256, 0, stream>>>(col, ghist, e, nbuck, chunk);
  k_s1     <<<nbuck, 256, 0, stream>>>(ghist, btotal, nbuck);
  k_s2     <<<1, 512, 0, stream>>>(btotal, bstart, nbuck, e, rowp, n);
  k_scatter<<<256, 256, 0, stream>>>(row, col, ghist, bstart, bpack, e, nbuck, chunk);
  k_bsort  <<<nbuck, 256, 0, stream>>>(bpack, bstart, rowp, dis, srci, n);
  k_gemm1_mfma<<<nb64, 256, 0, stream>>>(x, WB1, h1b, n);
  k_spmm1_bf<<<(n + 15) / 16, 256, 0, stream>>>(h1b, dis, rowp, srci, b1, aggb, n);
  k_bnstats<<<512, 256, 0, stream>>>(aggb, stats, n);
  k_gemm2_mfma<<<nb64, 256, 0, stream>>>(aggb, WB2, stats, gamma, beta, h2b, n);
  k_spmm2_bf<<<(n + 31) / 32, 256, 0, stream>>>(h2b, dis, rowp, srci, b2, out, n);
}